// Round 4
// baseline (1004.645 us; speedup 1.0000x reference)
//
#include <hip/hip_runtime.h>

typedef _Float16 f16;
typedef f16  f16x8 __attribute__((ext_vector_type(8)));
typedef f16  f16x4 __attribute__((ext_vector_type(4)));
typedef float f32x4 __attribute__((ext_vector_type(4)));

#define LOAD_LDS16(gp, lp) __builtin_amdgcn_global_load_lds( \
    (const __attribute__((address_space(1))) void*)(gp),     \
    (__attribute__((address_space(3))) void*)(lp), 16, 0, 0)

// ---------------- 8-phase GEMM machinery (kernel-local names expected:
// NKC, Al, Bl, tid, pa0, pa1, pb0, pb1, arow, brow, qa, ava, avb, bvv, acc)
#define BARX() __builtin_amdgcn_s_barrier()
#define SB0() __builtin_amdgcn_sched_barrier(0)
#define WLG0() asm volatile("s_waitcnt lgkmcnt(0)" ::: "memory")
#define WVM8() asm volatile("s_waitcnt vmcnt(8)" ::: "memory")
#define WVM0() asm volatile("s_waitcnt vmcnt(0)" ::: "memory")

// stage one 256x32 region (2 loads/thread). TT clamped at tail so the
// vmcnt(8) position-count stays exact; clamped stages land in free regions.
#define ST_A(TT, BB, KH) { \
  const long ko_ = (long)((TT) < NKC ? (TT) : (NKC - 1)) * 64 + (KH) * 32; \
  LOAD_LDS16(pa0 + ko_, &Al[BB][KH][tid * 8]); \
  LOAD_LDS16(pa1 + ko_, &Al[BB][KH][(512 + tid) * 8]); }
#define ST_B(TT, BB, KH) { \
  const long ko_ = (long)((TT) < NKC ? (TT) : (NKC - 1)) * 64 + (KH) * 32; \
  LOAD_LDS16(pb0 + ko_, &Bl[BB][KH][tid * 8]); \
  LOAD_LDS16(pb1 + ko_, &Bl[BB][KH][(512 + tid) * 8]); }

// balanced register loads: 4 A-frags (one row-half) or 4 B-frags per phase
#define RD_A4(DST, BB, KH, HB) _Pragma("unroll") \
  for (int i_ = 0; i_ < 4; i_++) \
    DST[i_] = *(const f16x8*)&Al[BB][KH][(arow + (HB) * 64 + i_ * 16) * 32 + qa];
#define RD_B4(BB, KH) _Pragma("unroll") \
  for (int j_ = 0; j_ < 4; j_++) \
    bvv[j_] = *(const f16x8*)&Bl[BB][KH][(brow + j_ * 16) * 32 + qa];
// 16-MFMA cluster: one row-half x full 64-col slab, one k-half
#define MFC(AV, OFF) \
  __builtin_amdgcn_s_setprio(1); \
  _Pragma("unroll") \
  for (int i_ = 0; i_ < 4; i_++) \
    _Pragma("unroll") \
    for (int j_ = 0; j_ < 4; j_++) \
      acc[(OFF) + i_][j_] = __builtin_amdgcn_mfma_f32_16x16x32_f16(AV[i_], bvv[j_], acc[(OFF) + i_][j_], 0, 0, 0); \
  __builtin_amdgcn_s_setprio(0);

// one K-tile (BK=64) = 4 phases, ds_reads balanced 8/4/8/4.
// Stage order & vmcnt(8) positions identical to the verified schedule:
// stages kh1 of tile KT+1 (phases 0,1), kh0 of tile KT+2 (phases 2,3).
#define GTILE(KT, BUF) { \
  RD_A4(ava, BUF, 0, 0) RD_B4(BUF, 0) \
  ST_A((KT) + 1, (BUF) ^ 1, 1) \
  BARX(); WLG0(); SB0(); \
  MFC(ava, 0) \
  SB0(); BARX(); \
  RD_A4(avb, BUF, 0, 1) \
  ST_B((KT) + 1, (BUF) ^ 1, 1) \
  WVM8(); \
  BARX(); WLG0(); SB0(); \
  MFC(avb, 4) \
  SB0(); BARX(); \
  RD_A4(ava, BUF, 1, 0) RD_B4(BUF, 1) \
  ST_A((KT) + 2, (BUF), 0) \
  BARX(); WLG0(); SB0(); \
  MFC(ava, 0) \
  SB0(); BARX(); \
  RD_A4(avb, BUF, 1, 1) \
  ST_B((KT) + 2, (BUF), 0) \
  WVM8(); \
  BARX(); WLG0(); SB0(); \
  MFC(avb, 4) \
  SB0(); BARX(); \
}

// ---------------------------------------------------------------- helpers

// two-source batched transpose: z < zsplit reads s0, else s1.
// src [z][R][C] fp32 -> dst (+z*dbatch) [c][r] fp16 with row stride dld
__global__ __launch_bounds__(256) void transpose_cast2(const float* __restrict__ s0,
                                                       const float* __restrict__ s1,
                                                       int zsplit, f16* __restrict__ dst,
                                                       int R, int C, long sbatch,
                                                       long dbatch, int dld) {
  __shared__ float tile[32][33];
  const int zc = blockIdx.x * 32;
  const int zr = blockIdx.y * 32;
  const int z  = blockIdx.z;
  const float* s = (z < zsplit) ? (s0 + (long)z * sbatch)
                                : (s1 + (long)(z - zsplit) * sbatch);
  f16* d = dst + (long)z * dbatch;
  const int tx = threadIdx.x & 31, ty = threadIdx.x >> 5;
#pragma unroll
  for (int rr = 0; rr < 32; rr += 8)
    tile[ty + rr][tx] = s[(long)(zr + ty + rr) * C + (zc + tx)];
  __syncthreads();
#pragma unroll
  for (int rr = 0; rr < 32; rr += 8)
    d[(long)(zc + ty + rr) * dld + (zr + tx)] = (f16)tile[tx][ty + rr];
}

// three independent small transposes in one launch (descriptor per z)
struct TDesc { const float* s; f16* d; int R; int C; int dld; };
struct TDesc3 { TDesc m[3]; };

__global__ __launch_bounds__(256) void transpose3(TDesc3 p) {
  const TDesc t = p.m[blockIdx.z];
  const int zc = blockIdx.x * 32;
  const int zr = blockIdx.y * 32;
  if (zr >= t.R || zc >= t.C) return;   // block-uniform exit
  __shared__ float tile[32][33];
  const int tx = threadIdx.x & 31, ty = threadIdx.x >> 5;
#pragma unroll
  for (int rr = 0; rr < 32; rr += 8)
    tile[ty + rr][tx] = t.s[(long)(zr + ty + rr) * t.C + (zc + tx)];
  __syncthreads();
#pragma unroll
  for (int rr = 0; rr < 32; rr += 8)
    t.d[(long)(zc + ty + rr) * t.dld + (zr + tx)] = (f16)tile[tx][ty + rr];
}

// gating: logits, top-4-of-12 (lists + per-row slot map), softmax(6)+entropy.
// Also emits xb (f16 cast of x) — castx fused in since every element is read here.
__global__ __launch_bounds__(256) void gating_kernel(
    const float* __restrict__ x, const float* __restrict__ gaw,
    const float* __restrict__ gab, const float* __restrict__ ggw,
    const float* __restrict__ ggb, f16* __restrict__ xb,
    float* __restrict__ wG, float* __restrict__ ent,
    int* __restrict__ rows, float* __restrict__ gval, int* __restrict__ cnt,
    int* __restrict__ eA, int* __restrict__ posA, float* __restrict__ wA4) {
  const int b = blockIdx.x, t = threadIdx.x;
  const float* xr = x + (long)b * 1024;
  float pa[12], pg[6];
#pragma unroll
  for (int e = 0; e < 12; e++) pa[e] = 0.f;
#pragma unroll
  for (int e = 0; e < 6; e++) pg[e] = 0.f;
  const int i0 = t * 4;
  const float4 xv = *(const float4*)(xr + i0);
  f16x4 hx; hx.x = (f16)xv.x; hx.y = (f16)xv.y; hx.z = (f16)xv.z; hx.w = (f16)xv.w;
  *(f16x4*)(xb + (long)b * 1024 + i0) = hx;
  const float xs[4] = {xv.x, xv.y, xv.z, xv.w};
#pragma unroll
  for (int u = 0; u < 4; u++) {
    const float xi = xs[u];
    const float* ga = gaw + (long)(i0 + u) * 12;
    const float* gg = ggw + (long)(i0 + u) * 6;
#pragma unroll
    for (int e = 0; e < 12; e++) pa[e] += xi * ga[e];
#pragma unroll
    for (int e = 0; e < 6; e++) pg[e] += xi * gg[e];
  }
#pragma unroll
  for (int e = 0; e < 12; e++)
    for (int m = 1; m < 64; m <<= 1) pa[e] += __shfl_xor(pa[e], m);
#pragma unroll
  for (int e = 0; e < 6; e++)
    for (int m = 1; m < 64; m <<= 1) pg[e] += __shfl_xor(pg[e], m);
  __shared__ float rw[4][18];
  const int lane = t & 63, wv = t >> 6;
  if (lane == 0) {
#pragma unroll
    for (int e = 0; e < 12; e++) rw[wv][e] = pa[e];
#pragma unroll
    for (int e = 0; e < 6; e++) rw[wv][12 + e] = pg[e];
  }
  __syncthreads();
  if (t == 0) {
    float la[12], lg[6];
#pragma unroll
    for (int e = 0; e < 12; e++)
      la[e] = rw[0][e] + rw[1][e] + rw[2][e] + rw[3][e] + gab[e];
#pragma unroll
    for (int e = 0; e < 6; e++)
      lg[e] = rw[0][12 + e] + rw[1][12 + e] + rw[2][12 + e] + rw[3][12 + e] + ggb[e];
    unsigned used = 0; float tv[4]; int tix[4];
    for (int k = 0; k < 4; k++) {
      float best = -3.4e38f; int bi = 0;
      for (int e = 0; e < 12; e++)
        if (!((used >> e) & 1u) && la[e] > best) { best = la[e]; bi = e; }
      tv[k] = best; tix[k] = bi; used |= 1u << bi;
    }
    const float mx = tv[0];
    float s = 0.f, w4[4];
    for (int k = 0; k < 4; k++) { w4[k] = expf(tv[k] - mx); s += w4[k]; }
    for (int k = 0; k < 4; k++) {
      const float w = w4[k] / s;
      const int e = tix[k];
      const int pos = atomicAdd(&cnt[e], 1);
      rows[e * 2048 + pos] = b;
      gval[e * 2048 + pos] = w;
      eA[b * 4 + k] = e;
      posA[b * 4 + k] = pos;
      wA4[b * 4 + k] = w;
    }
    float mg = lg[0];
    for (int e = 1; e < 6; e++) mg = fmaxf(mg, lg[e]);
    float sg = 0.f, wg6[6];
    for (int e = 0; e < 6; e++) { wg6[e] = expf(lg[e] - mg); sg += wg6[e]; }
    float H = 0.f;
    for (int e = 0; e < 6; e++) {
      const float w = wg6[e] / sg;
      wG[b * 6 + e] = w;
      H -= w * logf(w + 1e-8f);
    }
    ent[b] = H;
  }
}

__global__ void base_kernel(const int* __restrict__ cnt, int* __restrict__ baseA) {
  if (threadIdx.x == 0 && blockIdx.x == 0) {
    int r = 0;
    for (int e = 0; e < 12; e++) { baseA[e] = r; r += cnt[e]; }
  }
}

// combine: out_plus/out_minus from compact res + gate-weighted biases; tension0
__global__ __launch_bounds__(256) void combine_kernel(
    const f16* __restrict__ res, const int* __restrict__ eA,
    const int* __restrict__ posA, const float* __restrict__ wA4,
    const float* __restrict__ wG, const int* __restrict__ baseA,
    const float* __restrict__ ba2, const float* __restrict__ bg2,
    float* __restrict__ outP, float* __restrict__ outM,
    float* __restrict__ pt0, float* __restrict__ ts0) {
  const long b = blockIdx.x;
  const int t = threadIdx.x;
  const int c = t * 4;
  float4 P = {0.f, 0.f, 0.f, 0.f}, M = {0.f, 0.f, 0.f, 0.f};
#pragma unroll
  for (int k = 0; k < 4; k++) {
    const int e = eA[b * 4 + k];
    const long slot = baseA[e] + posA[b * 4 + k];
    const f16x4 v = *(const f16x4*)(res + slot * 1024 + c);
    const float w = wA4[b * 4 + k];
    const float4 bb = *(const float4*)(ba2 + (long)e * 1024 + c);
    P.x += (float)v.x + w * bb.x; P.y += (float)v.y + w * bb.y;
    P.z += (float)v.z + w * bb.z; P.w += (float)v.w + w * bb.w;
  }
#pragma unroll
  for (int e = 0; e < 6; e++) {
    const f16x4 v = *(const f16x4*)(res + (8192L + e * 2048 + b) * 1024 + c);
    const float w = wG[b * 6 + e];
    const float4 bb = *(const float4*)(bg2 + (long)e * 1024 + c);
    M.x += (float)v.x + w * bb.x; M.y += (float)v.y + w * bb.y;
    M.z += (float)v.z + w * bb.z; M.w += (float)v.w + w * bb.w;
  }
  *(float4*)(outP + b * 1024 + c) = P;
  *(float4*)(outM + b * 1024 + c) = M;
  const float dx = P.x - M.x, dy = P.y - M.y, dz = P.z - M.z, dw = P.w - M.w;
  float s = dx * dx + dy * dy + dz * dz + dw * dw;
#pragma unroll
  for (int m = 1; m < 64; m <<= 1) s += __shfl_xor(s, m);
  __shared__ float rw[4];
  if ((t & 63) == 0) rw[t >> 6] = s;
  __syncthreads();
  if (t == 0) {
    const float tot = rw[0] + rw[1] + rw[2] + rw[3];
    pt0[b] = tot;
    atomicAdd(ts0, tot);
  }
}

__global__ __launch_bounds__(256) void hsm_kernel(
    const float* __restrict__ pt, const float* __restrict__ tsum,
    const float* __restrict__ w1, const float* __restrict__ b1,
    f16* __restrict__ o, int step) {
  const int j = blockIdx.x * 256 + threadIdx.x;
  const int b0 = blockIdx.y * 64;
  const float u0 = w1[j], u1 = w1[2048 + j], u2 = w1[4096 + j], bb = b1[j];
  const float tm = tsum[0] * (1.f / 2048.f);
  const float st = (float)step * (1.f / 3.f);
#pragma unroll 4
  for (int r = 0; r < 64; r++) {
    const int b = b0 + r;
    const float t = pt[b];
    const float delta = (step == 0) ? 0.f : (t - tm);
    o[(long)b * 2048 + j] = (f16)tanhf(t * u0 + delta * u1 + st * u2 + bb);
  }
}

// ------------------------------------------------ unified GEMM1 (18 experts)
// h[row] = gate * relu(x[src_row] @ w1t[e18]^T + b1[e18])
// 8-phase, BM=BN=256, BK=64, 8 waves, 128 KiB LDS, counted vmcnt(8).
// PERSISTENT: grid=256 (1 block/CU), atomic work queue over 1152 virtual tiles
// (0..767 EngineA routed, 768..1151 EngineG dense); empty tiles skipped.
__global__ __launch_bounds__(512, 2) void gemm1_kernel(
    const f16* __restrict__ x, const f16* __restrict__ w1t,
    const float* __restrict__ ba1, const float* __restrict__ bg1,
    f16* __restrict__ h, const int* __restrict__ rows,
    const float* __restrict__ gval, const int* __restrict__ cnt,
    const int* __restrict__ baseA, const float* __restrict__ wG,
    int* __restrict__ wq) {
  constexpr int NKC = 16;                 // K=1024 / 64
  __shared__ f16 Al[2][2][8192];          // [dbuf][khalf][256 rows x 32 cols]
  __shared__ f16 Bl[2][2][8192];
  __shared__ int   Lrow[256];
  __shared__ float Lg[256];
  __shared__ int qv;
  const int tid = threadIdx.x;
  const int srow = tid >> 2;
  const int sch = ((tid & 3) ^ ((tid >> 3) & 3)) * 8;  // pre-swizzled source chunk
  const int wave = tid >> 6, lane = tid & 63;
  const int wm = wave & 1, wn = wave >> 1;
  const int l16 = lane & 15, qt = lane >> 4;
  const int qa = (qt ^ ((l16 >> 1) & 3)) * 8;
  const int arow = wm * 128 + l16;
  const int brow = wn * 64 + l16;
  for (;;) {
    if (tid == 0) qv = atomicAdd(wq, 1);
    __syncthreads();                      // broadcast + fence prev-tile LDS reads
    int id = qv;
    if (id >= 1152) return;
    int e18, mi, ni, live; long row0; const float* bp;
    if (id < 768) {                       // EngineA routed
      const int k = id & 7, t = id >> 3;
      mi = t & 7; const int pid = k * 12 + (t >> 3);
      const int e = pid >> 3; ni = pid & 7;
      live = cnt[e] - mi * 256;
      if (live > 256) live = 256;
      row0 = baseA[e] + mi * 256; e18 = e; bp = ba1 + (long)e * 2048;
    } else {
      const int id2 = id - 768;
      const int k = id2 & 7, t = id2 >> 3;
      mi = t & 7; const int pid = k * 6 + (t >> 3);
      const int e = pid >> 3; ni = pid & 7;
      row0 = 8192L + e * 2048 + mi * 256; live = 256;
      e18 = 12 + e; bp = bg1 + (long)e * 2048;
    }
    if (live <= 0) continue;              // block-uniform skip
    const bool routed = (e18 < 12);
    if (tid < 256) {
      const int gi = mi * 256 + tid;
      if (routed) {
        const bool ok = tid < live;
        Lrow[tid] = ok ? rows[e18 * 2048 + gi] : 0;
        Lg[tid]   = ok ? gval[e18 * 2048 + gi] : 0.f;
      } else {
        Lrow[tid] = gi;
        Lg[tid] = wG[gi * 6 + (e18 - 12)];
      }
    }
    __syncthreads();
    const f16* pa0 = x + (long)Lrow[srow] * 1024 + sch;
    const f16* pa1 = x + (long)Lrow[128 + srow] * 1024 + sch;
    const f16* pb0 = w1t + (long)e18 * 2048 * 1024 + ((long)ni * 256 + srow) * 1024 + sch;
    const f16* pb1 = pb0 + 128 * 1024;
    f32x4 acc[8][4] = {};
    f16x8 ava[4], avb[4], bvv[4];
    // prologue: tile0 (all 4 regions) + tile1 kh0 (prev epilogue stores drain here)
    ST_A(0, 0, 0) ST_B(0, 0, 0) ST_A(0, 0, 1) ST_B(0, 0, 1) ST_A(1, 1, 0) ST_B(1, 1, 0)
    WVM8(); BARX(); SB0();
#pragma unroll 1
    for (int kt = 0; kt < NKC; kt += 2) { GTILE(kt, 0) GTILE(kt + 1, 1) }
    WVM0();
    // epilogue: relu + gate + bias, store h (row stride 2048)
#pragma unroll
    for (int i = 0; i < 8; i++) {
#pragma unroll
      for (int r = 0; r < 4; r++) {
        const int lr = wm * 128 + i * 16 + qt * 4 + r;
        if (lr < live) {
          const float wv = Lg[lr];
          f16* C = h + (row0 + lr) * 2048 + ni * 256;
#pragma unroll
          for (int jj = 0; jj < 4; jj++) {
            const int cc = wn * 64 + jj * 16 + l16;
            const float v = fmaxf(acc[i][jj][r] + bp[ni * 256 + cc], 0.f) * wv;
            C[cc] = (f16)v;
          }
        }
      }
    }
  }
}

// ------------------------------------------------ unified GEMM2 (18 experts)
// res[row] = h[row] @ w2t[e18]^T ; 8-phase, BM=BN=256, BK=64, K=2048
// PERSISTENT: grid=256, atomic queue over 576 virtual tiles
// (0..383 EngineA routed, 384..575 EngineG dense).
__global__ __launch_bounds__(512, 2) void gemm2_kernel(
    const f16* __restrict__ h, const f16* __restrict__ w2t,
    f16* __restrict__ res, const int* __restrict__ cnt,
    const int* __restrict__ baseA, int* __restrict__ wq) {
  constexpr int NKC = 32;                 // K=2048 / 64
  __shared__ f16 Al[2][2][8192];
  __shared__ f16 Bl[2][2][8192];
  __shared__ int qv;
  const int tid = threadIdx.x;
  const int srow = tid >> 2;
  const int sch = ((tid & 3) ^ ((tid >> 3) & 3)) * 8;
  const int wave = tid >> 6, lane = tid & 63;
  const int wm = wave & 1, wn = wave >> 1;
  const int l16 = lane & 15, qt = lane >> 4;
  const int qa = (qt ^ ((l16 >> 1) & 3)) * 8;
  const int arow = wm * 128 + l16;
  const int brow = wn * 64 + l16;
  for (;;) {
    if (tid == 0) qv = atomicAdd(wq, 1);
    __syncthreads();
    int id = qv;
    if (id >= 576) return;
    int e18, mi, ni, live; long row0;
    if (id < 384) {                       // 12 exp * 8 mi * 4 ni
      const int k = id & 7, t = id >> 3;
      mi = t & 7; const int pid = k * 6 + (t >> 3);
      const int e = pid >> 2; ni = pid & 3;
      live = cnt[e] - mi * 256;
      if (live > 256) live = 256;
      row0 = baseA[e] + mi * 256; e18 = e;
    } else {
      const int id2 = id - 384;           // 6 exp * 8 mi * 4 ni
      const int k = id2 & 7, t = id2 >> 3;
      mi = t & 7; const int pid = k * 3 + (t >> 3);
      const int e = pid >> 2; ni = pid & 3;
      row0 = 8192L + e * 2048 + mi * 256; live = 256; e18 = 12 + e;
    }
    if (live <= 0) continue;
    const f16* pa0 = h + (row0 + srow) * 2048 + sch;
    const f16* pa1 = pa0 + 128 * 2048;
    const f16* pb0 = w2t + (long)e18 * 1024 * 2048 + ((long)ni * 256 + srow) * 2048 + sch;
    const f16* pb1 = pb0 + 128 * 2048;
    f32x4 acc[8][4] = {};
    f16x8 ava[4], avb[4], bvv[4];
    ST_A(0, 0, 0) ST_B(0, 0, 0) ST_A(0, 0, 1) ST_B(0, 0, 1) ST_A(1, 1, 0) ST_B(1, 1, 0)
    WVM8(); BARX(); SB0();
#pragma unroll 1
    for (int kt = 0; kt < NKC; kt += 2) { GTILE(kt, 0) GTILE(kt + 1, 1) }
    WVM0();
#pragma unroll
    for (int i = 0; i < 8; i++) {
#pragma unroll
      for (int r = 0; r < 4; r++) {
        const int lr = wm * 128 + i * 16 + qt * 4 + r;
        if (lr < live) {
          f16* C = res + (row0 + lr) * 1024 + ni * 256 + wn * 64 + l16;
#pragma unroll
          for (int jj = 0; jj < 4; jj++) C[jj * 16] = (f16)acc[i][jj][r];
        }
      }
    }
  }
}

// ------------------------------------------------ small dense GEMM (dbuf)
// BK=64; LDS rows 128 B; chunk swizzle phys = (hf*4+q) ^ (row&7), staged via
// pre-swizzled global source (linear LDS dest), read with same involution.

struct GA {
  const f16* A; long lda;
  const f16* B; long ldb;
  int nk;                      // K / 64
  float* Cf; f16* Ch;
  const float* bias;
  const float* op; const float* om;
  const float* pt; const float* ts;
  float* pt_out; float* tsum_out;
  const float* ent; const float* tsb; float* aux_out;  // EPI==4 aux fusion
};

// BM=BN=64. EPI: 2 tanh->f16 ; 3 mod+tension ; 4 final output (+aux in block 0,0)
template <int EPI>
__global__ __launch_bounds__(256) void gemm_s(GA a) {
  __shared__ f16 Al[2][64 * 64];
  __shared__ f16 Bl[2][64 * 64];
  const int tid = threadIdx.x;
  const int wave = tid >> 6, lane = tid & 63;
  const int wm = wave & 1, wn = wave >> 1;
  const int l16 = lane & 15, q = lane >> 4;
  const long m0 = (long)blockIdx.y * 64;
  const long n0 = (long)blockIdx.x * 64;
  const int srow = tid >> 3;
  const int sch  = ((tid & 7) ^ (srow & 7)) * 8;
  const f16* a0 = a.A + (m0 + srow) * a.lda + sch;
  const f16* a1 = a.A + (m0 + srow + 32) * a.lda + sch;
  const f16* b0 = a.B + (n0 + srow) * a.ldb + sch;
  const f16* b1 = a.B + (n0 + srow + 32) * a.ldb + sch;
  const int rx = (l16 & 7) * 8;
  f32x4 acc[2][2] = {};
  LOAD_LDS16(a0, &Al[0][tid * 8]);
  LOAD_LDS16(a1, &Al[0][(256 + tid) * 8]);
  LOAD_LDS16(b0, &Bl[0][tid * 8]);
  LOAD_LDS16(b1, &Bl[0][(256 + tid) * 8]);
  for (int kk = 0; kk < a.nk; ++kk) {
    __syncthreads();
    const int cur = kk & 1;
    if (kk + 1 < a.nk) {
      const long k0 = (long)(kk + 1) * 64;
      const int nb = cur ^ 1;
      LOAD_LDS16(a0 + k0, &Al[nb][tid * 8]);
      LOAD_LDS16(a1 + k0, &Al[nb][(256 + tid) * 8]);
      LOAD_LDS16(b0 + k0, &Bl[nb][tid * 8]);
      LOAD_LDS16(b1 + k0, &Bl[nb][(256 + tid) * 8]);
    }
    f16x8 avv[2][2], bvv[2][2];
#pragma unroll
    for (int hf = 0; hf < 2; hf++) {
      const int cA = (((hf * 4 + q) * 8) ^ rx);
#pragma unroll
      for (int i = 0; i < 2; i++)
        avv[hf][i] = *(const f16x8*)&Al[cur][(wm * 32 + i * 16 + l16) * 64 + cA];
#pragma unroll
      for (int j = 0; j < 2; j++)
        bvv[hf][j] = *(const f16x8*)&Bl[cur][(wn * 32 + j * 16 + l16) * 64 + cA];
    }
#pragma unroll
    for (int hf = 0; hf < 2; hf++)
#pragma unroll
      for (int i = 0; i < 2; i++)
#pragma unroll
        for (int j = 0; j < 2; j++)
          acc[i][j] = __builtin_amdgcn_mfma_f32_16x16x32_f16(avv[hf][i], bvv[hf][j], acc[i][j], 0, 0, 0);
  }
  if constexpr (EPI == 2) {
#pragma unroll
    for (int i = 0; i < 2; i++)
#pragma unroll
      for (int r = 0; r < 4; r++) {
        const long gr = m0 + wm * 32 + i * 16 + q * 4 + r;
#pragma unroll
        for (int j = 0; j < 2; j++) {
          const int gc = (int)n0 + wn * 32 + j * 16 + l16;
          a.Ch[gr * 1024 + gc] = (f16)tanhf(acc[i][j][r] + a.bias[gc]);
        }
      }
  } else if constexpr (EPI == 3) {
    float wave_ss = 0.f;
#pragma unroll
    for (int i = 0; i < 2; i++)
#pragma unroll
      for (int r = 0; r < 4; r++) {
        const long gr = m0 + wm * 32 + i * 16 + q * 4 + r;
        float ss = 0.f;
#pragma unroll
        for (int j = 0; j < 2; j++) {
          const int gc = (int)n0 + wn * 32 + j * 16 + l16;
          const long ix = gr * 1024 + gc;
          const float v = (a.op[ix] - a.om[ix]) + acc[i][j][r] + a.bias[gc];
          a.Ch[ix] = (f16)v;
          ss += v * v;
        }
        ss += __shfl_xor(ss, 1); ss += __shfl_xor(ss, 2);
        ss += __shfl_xor(ss, 4); ss += __shfl_xor(ss, 8);
        if (l16 == 0) {
          atomicAdd(a.pt_out + gr, ss);
          wave_ss += ss;
        }
      }
    wave_ss += __shfl_xor(wave_ss, 16);
    wave_ss += __shfl_xor(wave_ss, 32);
    if (lane == 0) atomicAdd(a.tsum_out, wave_ss);
  } else {  // EPI == 4
    const float tsc = a.ts[0];
#pragma unroll
    for (int i = 0; i < 2; i++)
#pragma unroll
      for (int r = 0; r < 4; r++) {
        const long gr = m0 + wm * 32 + i * 16 + q * 4 + r;
        const float sq = sqrtf(a.pt[gr] + 1e-8f) * tsc;
#pragma unroll
        for (int j = 0; j < 2; j++) {
          const int gc = (int)n0 + wn * 32 + j * 16 + l16;
          const long ix = gr * 1024 + gc;
          const float v = tanhf(acc[i][j][r] + a.bias[gc]);
          a.Cf[ix] = 0.5f * (a.op[ix] + a.om[ix]) + sq * v;
        }
      }
    // aux loss fused into block (0,0): all tsb[0..3] were written before launch
    if (blockIdx.x == 0 && blockIdx.y == 0) {
      float s = 0.f;
      for (int i = tid; i < 2048; i += 256) s += a.ent[i];
#pragma unroll
      for (int m = 1; m < 64; m <<= 1) s += __shfl_xor(s, m);
      __shared__ float rwa[4];
      if ((tid & 63) == 0) rwa[tid >> 6] = s;
      __syncthreads();
      if (tid == 0) {
        const float hh = (rwa[0] + rwa[1] + rwa[2] + rwa[3]) * (1.f / 2048.f);
        const float dd = hh - 1.0114042647f;
        const float el = dd * dd;
        const float t0 = a.tsb[0] * (1.f / 2048.f), t1 = a.tsb[1] * (1.f / 2048.f);
        const float t2 = a.tsb[2] * (1.f / 2048.f), t3 = a.tsb[3] * (1.f / 2048.f);
        const float conv = (fabsf(t1 - t0) + fabsf(t2 - t1) + fabsf(t3 - t2)) * (1.f / 3.f);
        a.aux_out[0] = el + 0.001f * conv;
      }
    }
  }
}

// ---------------------------------------------------------------- launcher

extern "C" void kernel_launch(void* const* d_in, const int* in_sizes, int n_in,
                              void* d_out, int out_size, void* d_ws, size_t ws_size,
                              hipStream_t stream) {
  (void)in_sizes; (void)n_in; (void)out_size; (void)ws_size;
  const float* x    = (const float*)d_in[0];
  const float* gaw  = (const float*)d_in[1];
  const float* gab  = (const float*)d_in[2];
  const float* wa1  = (const float*)d_in[3];
  const float* ba1  = (const float*)d_in[4];
  const float* wa2  = (const float*)d_in[5];
  const float* ba2  = (const float*)d_in[6];
  const float* ggw  = (const float*)d_in[7];
  const float* ggb  = (const float*)d_in[8];
  const float* wg1  = (const float*)d_in[9];
  const float* bg1  = (const float*)d_in[10];
  const float* wg2  = (const float*)d_in[11];
  const float* bg2  = (const float*)d_in[12];
  const float* smw1 = (const float*)d_in[13];
  const float* smb1 = (const float*)d_in[14];
  const float* smw2 = (const float*)d_in[15];
  const float* smb2 = (const float*)d_in[16];
  const float* siw  = (const float*)d_in[17];
  const float* sib  = (const float*)d_in[18];
  const float* ftw  = (const float*)d_in[19];
  const float* ftb  = (const float*)d_in[20];
  const float* tsc  = (const float*)d_in[21];

  char* p = (char*)d_ws;
  size_t off = 0;
  auto alloc = [&](size_t bytes) -> char* {
    char* r = p + off;
    off = (off + bytes + 255) & ~(size_t)255;
    return r;
  };
  f16* xb     = (f16*)alloc(2048UL * 1024 * 2);
  f16* w1t    = (f16*)alloc(18UL * 2048 * 1024 * 2);   // later reused as w2t
  f16* smw2t  = (f16*)alloc(1024UL * 2048 * 2);
  f16* sit    = (f16*)alloc(1024UL * 1024 * 2);
  f16* ftt    = (f16*)alloc(1024UL * 1024 * 2);
  f16* h      = (f16*)alloc(20480UL * 2048 * 2);       // 8192 A-compact + 6*2048 G
  f16* res    = (f16*)alloc(20480UL * 1024 * 2);
  float* outP = (float*)alloc(2048UL * 1024 * 4);
  float* outM = (float*)alloc(2048UL * 1024 * 4);
  f16* hsmb   = (f16*)alloc(2048UL * 2048 * 2);
  f16* sst    = (f16*)alloc(2048UL * 1024 * 2);
  f16* modb   = (f16*)alloc(2048UL * 1024 * 2);
  float* entb = (float*)alloc(2048 * 4);
  float* wGb  = (float*)alloc(2048 * 6 * 4);
  float* ptb  = (float*)alloc(4 * 2048 * 4);           // 32768 B
  float* tsb  = (float*)alloc(4 * 4);                  // 256-B slot; tail zeroed
  int*   cntb = (int*)alloc(12 * 4);
  int*   baseAb = (int*)alloc(12 * 4);
  int*   rowsb  = (int*)alloc(12 * 2048 * 4);
  float* gvalb  = (float*)alloc(12 * 2048 * 4);
  int*   eAb    = (int*)alloc(2048 * 4 * 4);
  int*   posAb  = (int*)alloc(2048 * 4 * 4);
  float* wA4b   = (float*)alloc(2048 * 4 * 4);

  f16* w2t = w1t;  // [18][1024][2048], reused after gemm1
  // work-queue counters live in the zeroed slack of tsb's 256-B slot
  int* qq = (int*)((char*)tsb + 64);

  // zero tension accumulators + queue counters + expert counters (contiguous)
  hipMemsetAsync(ptb, 0, 33072, stream);

  // weight conversion + transpose to [N][K] fp16 (wa1+wg1 in ONE launch)
  transpose_cast2<<<dim3(64, 32, 18), 256, 0, stream>>>(wa1, wg1, 12, w1t,
      1024, 2048, 1024L * 2048, 2048L * 1024, 1024);
  // the three small transposes in ONE launch
  {
    TDesc3 td;
    td.m[0] = {smw2, smw2t, 2048, 1024, 2048};
    td.m[1] = {siw,  sit,  1024, 1024, 1024};
    td.m[2] = {ftw,  ftt,  1024, 1024, 1024};
    transpose3<<<dim3(32, 64, 3), 256, 0, stream>>>(td);
  }
  gating_kernel<<<2048, 256, 0, stream>>>(x, gaw, gab, ggw, ggb, xb, wGb, entb,
                                          rowsb, gvalb, cntb, eAb, posAb, wA4b);
  base_kernel<<<1, 64, 0, stream>>>(cntb, baseAb);

  // unified GEMM1 (A routed + G dense), persistent 8-phase 256^2
  gemm1_kernel<<<256, 512, 0, stream>>>(xb, w1t, ba1, bg1, h,
                                        rowsb, gvalb, cntb, baseAb, wGb, qq);

  // layer-2 weights into the (now dead) w1t region (wa2+wg2 in ONE launch)
  transpose_cast2<<<dim3(32, 64, 18), 256, 0, stream>>>(wa2, wg2, 12, w2t,
      2048, 1024, 2048L * 1024, 1024L * 2048, 2048);

  // unified GEMM2, persistent 8-phase 256^2, compact f16 out, no atomics
  gemm2_kernel<<<256, 512, 0, stream>>>(h, w2t, res, cntb, baseAb, qq + 1);

  combine_kernel<<<2048, 256, 0, stream>>>(res, eAb, posAb, wA4b, wGb, baseAb,
                                           ba2, bg2, outP, outM, ptb, tsb);

  for (int s = 0; s < 3; s++) {
    hsm_kernel<<<dim3(8, 32), 256, 0, stream>>>(ptb + s * 2048, tsb + s, smw1, smb1, hsmb, s);
    GA g3{};
    g3.A = hsmb; g3.lda = 2048; g3.B = smw2t; g3.ldb = 2048; g3.nk = 32;
    g3.Ch = sst; g3.bias = smb2;
    gemm_s<2><<<dim3(16, 32), 256, 0, stream>>>(g3);
    GA g4{};
    g4.A = sst; g4.lda = 1024; g4.B = sit; g4.ldb = 1024; g4.nk = 16;
    g4.Ch = modb; g4.bias = sib; g4.op = outP; g4.om = outM;
    g4.pt_out = ptb + (s + 1) * 2048; g4.tsum_out = tsb + (s + 1);
    gemm_s<3><<<dim3(16, 32), 256, 0, stream>>>(g4);
  }

  GA g5{};
  g5.A = modb; g5.lda = 1024; g5.B = ftt; g5.ldb = 1024; g5.nk = 16;
  g5.Cf = (float*)d_out; g5.bias = ftb; g5.op = outP; g5.om = outM;
  g5.pt = ptb + 3 * 2048; g5.ts = tsc;
  g5.ent = entb; g5.tsb = tsb; g5.aux_out = (float*)d_out + 2048UL * 1024;
  gemm_s<4><<<dim3(16, 32), 256, 0, stream>>>(g5);
}

// Round 5
// 991.532 us; speedup vs baseline: 1.0132x; 1.0132x over previous
//
#include <hip/hip_runtime.h>

typedef _Float16 f16;
typedef f16  f16x8 __attribute__((ext_vector_type(8)));
typedef f16  f16x4 __attribute__((ext_vector_type(4)));
typedef float f32x4 __attribute__((ext_vector_type(4)));

#define LOAD_LDS16(gp, lp) __builtin_amdgcn_global_load_lds( \
    (const __attribute__((address_space(1))) void*)(gp),     \
    (__attribute__((address_space(3))) void*)(lp), 16, 0, 0)

// ---------------- 8-phase GEMM machinery (kernel-local names expected:
// NKC, Al, Bl, tid, pa0, pa1, pb0, pb1, arow, brow, qa, av, bv, acc)
#define BARX() __builtin_amdgcn_s_barrier()
#define SB0() __builtin_amdgcn_sched_barrier(0)
#define WLG0() asm volatile("s_waitcnt lgkmcnt(0)" ::: "memory")
#define WVM8() asm volatile("s_waitcnt vmcnt(8)" ::: "memory")
#define WVM0() asm volatile("s_waitcnt vmcnt(0)" ::: "memory")

// stage one 256x32 region (2 loads/thread). TT clamped at tail so the
// vmcnt(8) position-count stays exact; clamped stages land in free regions.
#define ST_A(TT, BB, KH) { \
  const long ko_ = (long)((TT) < NKC ? (TT) : (NKC - 1)) * 64 + (KH) * 32; \
  LOAD_LDS16(pa0 + ko_, &Al[BB][KH][tid * 8]); \
  LOAD_LDS16(pa1 + ko_, &Al[BB][KH][(512 + tid) * 8]); }
#define ST_B(TT, BB, KH) { \
  const long ko_ = (long)((TT) < NKC ? (TT) : (NKC - 1)) * 64 + (KH) * 32; \
  LOAD_LDS16(pb0 + ko_, &Bl[BB][KH][tid * 8]); \
  LOAD_LDS16(pb1 + ko_, &Bl[BB][KH][(512 + tid) * 8]); }

#define RD_AV(BB, KH) _Pragma("unroll") \
  for (int i_ = 0; i_ < 8; i_++) \
    av[i_] = *(const f16x8*)&Al[BB][KH][(arow + i_ * 16) * 32 + qa];
#define RD_BV(BB, KH, CB) _Pragma("unroll") \
  for (int j_ = 0; j_ < 2; j_++) \
    bv[j_] = *(const f16x8*)&Bl[BB][KH][(brow + (CB) * 32 + j_ * 16) * 32 + qa];
#define MF16(CB) \
  __builtin_amdgcn_s_setprio(1); \
  _Pragma("unroll") \
  for (int i_ = 0; i_ < 8; i_++) { \
    acc[i_][2 * (CB)]     = __builtin_amdgcn_mfma_f32_16x16x32_f16(av[i_], bv[0], acc[i_][2 * (CB)], 0, 0, 0); \
    acc[i_][2 * (CB) + 1] = __builtin_amdgcn_mfma_f32_16x16x32_f16(av[i_], bv[1], acc[i_][2 * (CB) + 1], 0, 0, 0); \
  } \
  __builtin_amdgcn_s_setprio(0);

// one K-tile (BK=64) = 4 phases. Stages: kh1 of tile KT+1 (phases 0,1),
// kh0 of tile KT+2 (phases 2,3). vmcnt(8) at phases 1,3 guards the reads
// happening 1-2 phases later (8 loads issued since the guarded stage).
#define GTILE(KT, BUF) { \
  RD_AV(BUF, 0) RD_BV(BUF, 0, 0) \
  ST_A((KT) + 1, (BUF) ^ 1, 1) \
  BARX(); WLG0(); SB0(); \
  MF16(0) \
  SB0(); BARX(); \
  RD_BV(BUF, 0, 1) \
  ST_B((KT) + 1, (BUF) ^ 1, 1) \
  WVM8(); \
  BARX(); WLG0(); SB0(); \
  MF16(1) \
  SB0(); BARX(); \
  RD_AV(BUF, 1) RD_BV(BUF, 1, 0) \
  ST_A((KT) + 2, (BUF), 0) \
  BARX(); WLG0(); SB0(); \
  MF16(0) \
  SB0(); BARX(); \
  RD_BV(BUF, 1, 1) \
  ST_B((KT) + 2, (BUF), 0) \
  WVM8(); \
  BARX(); WLG0(); SB0(); \
  MF16(1) \
  SB0(); BARX(); \
}

// ---------------------------------------------------------------- helpers

// 64x64 transpose-cast tile: float4 global loads, f16x4 global stores,
// LDS [64][65] with 2-way-max bank aliasing (free) on both phases.
__device__ __forceinline__ void tr64_tile(const float* __restrict__ s,
                                          f16* __restrict__ d, int C, int dld,
                                          int zr, int zc, int tid) {
  __shared__ float tile[64][65];
  const int tx = tid & 15, ty = tid >> 4;
#pragma unroll
  for (int i = 0; i < 4; i++) {
    const int r = ty + i * 16;
    const float4 v = *(const float4*)(s + (long)(zr + r) * C + zc + tx * 4);
    tile[r][tx * 4 + 0] = v.x; tile[r][tx * 4 + 1] = v.y;
    tile[r][tx * 4 + 2] = v.z; tile[r][tx * 4 + 3] = v.w;
  }
  __syncthreads();
#pragma unroll
  for (int i = 0; i < 4; i++) {
    const int oc = ty + i * 16;                  // source col = dest row
    f16x4 h4;
    h4.x = (f16)tile[tx * 4 + 0][oc];
    h4.y = (f16)tile[tx * 4 + 1][oc];
    h4.z = (f16)tile[tx * 4 + 2][oc];
    h4.w = (f16)tile[tx * 4 + 3][oc];
    *(f16x4*)(d + (long)(zc + oc) * dld + zr + tx * 4) = h4;
  }
}

// two-source batched transpose: z < zsplit reads s0, else s1.
// src [z][R][C] fp32 -> dst (+z*dbatch) [c][r] fp16 with row stride dld
__global__ __launch_bounds__(256) void transpose_cast2(const float* __restrict__ s0,
                                                       const float* __restrict__ s1,
                                                       int zsplit, f16* __restrict__ dst,
                                                       int R, int C, long sbatch,
                                                       long dbatch, int dld) {
  const int z = blockIdx.z;
  const float* s = (z < zsplit) ? (s0 + (long)z * sbatch)
                                : (s1 + (long)(z - zsplit) * sbatch);
  tr64_tile(s, dst + (long)z * dbatch, C, dld,
            blockIdx.y * 64, blockIdx.x * 64, threadIdx.x);
}

// three independent small transposes in one launch (descriptor per z)
struct TDesc { const float* s; f16* d; int R; int C; int dld; };
struct TDesc3 { TDesc m[3]; };

__global__ __launch_bounds__(256) void transpose3(TDesc3 p) {
  const TDesc t = p.m[blockIdx.z];
  const int zc = blockIdx.x * 64;
  const int zr = blockIdx.y * 64;
  if (zr >= t.R || zc >= t.C) return;   // block-uniform exit
  tr64_tile(t.s, t.d, t.C, t.dld, zr, zc, threadIdx.x);
}

// gating: logits, top-4-of-12 (lists + per-row slot map), softmax(6)+entropy.
// Also emits xb (f16 cast of x) — castx fused in since every element is read here.
__global__ __launch_bounds__(256) void gating_kernel(
    const float* __restrict__ x, const float* __restrict__ gaw,
    const float* __restrict__ gab, const float* __restrict__ ggw,
    const float* __restrict__ ggb, f16* __restrict__ xb,
    float* __restrict__ wG, float* __restrict__ ent,
    int* __restrict__ rows, float* __restrict__ gval, int* __restrict__ cnt,
    int* __restrict__ eA, int* __restrict__ posA, float* __restrict__ wA4) {
  const int b = blockIdx.x, t = threadIdx.x;
  const float* xr = x + (long)b * 1024;
  float pa[12], pg[6];
#pragma unroll
  for (int e = 0; e < 12; e++) pa[e] = 0.f;
#pragma unroll
  for (int e = 0; e < 6; e++) pg[e] = 0.f;
  const int i0 = t * 4;
  const float4 xv = *(const float4*)(xr + i0);
  f16x4 hx; hx.x = (f16)xv.x; hx.y = (f16)xv.y; hx.z = (f16)xv.z; hx.w = (f16)xv.w;
  *(f16x4*)(xb + (long)b * 1024 + i0) = hx;
  const float xs[4] = {xv.x, xv.y, xv.z, xv.w};
#pragma unroll
  for (int u = 0; u < 4; u++) {
    const float xi = xs[u];
    const float* ga = gaw + (long)(i0 + u) * 12;
    const float* gg = ggw + (long)(i0 + u) * 6;
#pragma unroll
    for (int e = 0; e < 12; e++) pa[e] += xi * ga[e];
#pragma unroll
    for (int e = 0; e < 6; e++) pg[e] += xi * gg[e];
  }
#pragma unroll
  for (int e = 0; e < 12; e++)
    for (int m = 1; m < 64; m <<= 1) pa[e] += __shfl_xor(pa[e], m);
#pragma unroll
  for (int e = 0; e < 6; e++)
    for (int m = 1; m < 64; m <<= 1) pg[e] += __shfl_xor(pg[e], m);
  __shared__ float rw[4][18];
  const int lane = t & 63, wv = t >> 6;
  if (lane == 0) {
#pragma unroll
    for (int e = 0; e < 12; e++) rw[wv][e] = pa[e];
#pragma unroll
    for (int e = 0; e < 6; e++) rw[wv][12 + e] = pg[e];
  }
  __syncthreads();
  if (t == 0) {
    float la[12], lg[6];
#pragma unroll
    for (int e = 0; e < 12; e++)
      la[e] = rw[0][e] + rw[1][e] + rw[2][e] + rw[3][e] + gab[e];
#pragma unroll
    for (int e = 0; e < 6; e++)
      lg[e] = rw[0][12 + e] + rw[1][12 + e] + rw[2][12 + e] + rw[3][12 + e] + ggb[e];
    unsigned used = 0; float tv[4]; int tix[4];
    for (int k = 0; k < 4; k++) {
      float best = -3.4e38f; int bi = 0;
      for (int e = 0; e < 12; e++)
        if (!((used >> e) & 1u) && la[e] > best) { best = la[e]; bi = e; }
      tv[k] = best; tix[k] = bi; used |= 1u << bi;
    }
    const float mx = tv[0];
    float s = 0.f, w4[4];
    for (int k = 0; k < 4; k++) { w4[k] = expf(tv[k] - mx); s += w4[k]; }
    for (int k = 0; k < 4; k++) {
      const float w = w4[k] / s;
      const int e = tix[k];
      const int pos = atomicAdd(&cnt[e], 1);
      rows[e * 2048 + pos] = b;
      gval[e * 2048 + pos] = w;
      eA[b * 4 + k] = e;
      posA[b * 4 + k] = pos;
      wA4[b * 4 + k] = w;
    }
    float mg = lg[0];
    for (int e = 1; e < 6; e++) mg = fmaxf(mg, lg[e]);
    float sg = 0.f, wg6[6];
    for (int e = 0; e < 6; e++) { wg6[e] = expf(lg[e] - mg); sg += wg6[e]; }
    float H = 0.f;
    for (int e = 0; e < 6; e++) {
      const float w = wg6[e] / sg;
      wG[b * 6 + e] = w;
      H -= w * logf(w + 1e-8f);
    }
    ent[b] = H;
  }
}

__global__ void base_kernel(const int* __restrict__ cnt, int* __restrict__ baseA) {
  if (threadIdx.x == 0 && blockIdx.x == 0) {
    int r = 0;
    for (int e = 0; e < 12; e++) { baseA[e] = r; r += cnt[e]; }
  }
}

// combine: out_plus/out_minus from compact res + gate-weighted biases; tension0
__global__ __launch_bounds__(256) void combine_kernel(
    const f16* __restrict__ res, const int* __restrict__ eA,
    const int* __restrict__ posA, const float* __restrict__ wA4,
    const float* __restrict__ wG, const int* __restrict__ baseA,
    const float* __restrict__ ba2, const float* __restrict__ bg2,
    float* __restrict__ outP, float* __restrict__ outM,
    float* __restrict__ pt0, float* __restrict__ ts0) {
  const long b = blockIdx.x;
  const int t = threadIdx.x;
  const int c = t * 4;
  float4 P = {0.f, 0.f, 0.f, 0.f}, M = {0.f, 0.f, 0.f, 0.f};
#pragma unroll
  for (int k = 0; k < 4; k++) {
    const int e = eA[b * 4 + k];
    const long slot = baseA[e] + posA[b * 4 + k];
    const f16x4 v = *(const f16x4*)(res + slot * 1024 + c);
    const float w = wA4[b * 4 + k];
    const float4 bb = *(const float4*)(ba2 + (long)e * 1024 + c);
    P.x += (float)v.x + w * bb.x; P.y += (float)v.y + w * bb.y;
    P.z += (float)v.z + w * bb.z; P.w += (float)v.w + w * bb.w;
  }
#pragma unroll
  for (int e = 0; e < 6; e++) {
    const f16x4 v = *(const f16x4*)(res + (8192L + e * 2048 + b) * 1024 + c);
    const float w = wG[b * 6 + e];
    const float4 bb = *(const float4*)(bg2 + (long)e * 1024 + c);
    M.x += (float)v.x + w * bb.x; M.y += (float)v.y + w * bb.y;
    M.z += (float)v.z + w * bb.z; M.w += (float)v.w + w * bb.w;
  }
  *(float4*)(outP + b * 1024 + c) = P;
  *(float4*)(outM + b * 1024 + c) = M;
  const float dx = P.x - M.x, dy = P.y - M.y, dz = P.z - M.z, dw = P.w - M.w;
  float s = dx * dx + dy * dy + dz * dz + dw * dw;
#pragma unroll
  for (int m = 1; m < 64; m <<= 1) s += __shfl_xor(s, m);
  __shared__ float rw[4];
  if ((t & 63) == 0) rw[t >> 6] = s;
  __syncthreads();
  if (t == 0) {
    const float tot = rw[0] + rw[1] + rw[2] + rw[3];
    pt0[b] = tot;
    atomicAdd(ts0, tot);
  }
}

__global__ __launch_bounds__(256) void hsm_kernel(
    const float* __restrict__ pt, const float* __restrict__ tsum,
    const float* __restrict__ w1, const float* __restrict__ b1,
    f16* __restrict__ o, int step) {
  const int j = blockIdx.x * 256 + threadIdx.x;
  const int b0 = blockIdx.y * 64;
  const float u0 = w1[j], u1 = w1[2048 + j], u2 = w1[4096 + j], bb = b1[j];
  const float tm = tsum[0] * (1.f / 2048.f);
  const float st = (float)step * (1.f / 3.f);
#pragma unroll 4
  for (int r = 0; r < 64; r++) {
    const int b = b0 + r;
    const float t = pt[b];
    const float delta = (step == 0) ? 0.f : (t - tm);
    o[(long)b * 2048 + j] = (f16)tanhf(t * u0 + delta * u1 + st * u2 + bb);
  }
}

// ------------------------------------------------ unified GEMM1 (18 experts)
// h[row] = gate * relu(x[src_row] @ w1t[e18]^T + b1[e18])
// 8-phase schedule: BM=BN=256, BK=64, 8 waves, 128 KiB LDS, counted vmcnt(8).
// grid 1152: ids 0..767 EngineA routed, 768..1151 EngineG dense. Static
// XCD-major mapping (k = id&7 owns (e,ni); mi fast) — preserves per-XCD
// B-panel L2 affinity (persistent-queue variant doubled FETCH_SIZE; reverted).
__global__ __launch_bounds__(512, 2) void gemm1_kernel(
    const f16* __restrict__ x, const f16* __restrict__ w1t,
    const float* __restrict__ ba1, const float* __restrict__ bg1,
    f16* __restrict__ h, const int* __restrict__ rows,
    const float* __restrict__ gval, const int* __restrict__ cnt,
    const int* __restrict__ baseA, const float* __restrict__ wG) {
  constexpr int NKC = 16;                 // K=1024 / 64
  __shared__ f16 Al[2][2][8192];          // [dbuf][khalf][256 rows x 32 cols]
  __shared__ f16 Bl[2][2][8192];
  __shared__ int   Lrow[256];
  __shared__ float Lg[256];
  int id = blockIdx.x;
  int e18, mi, ni, live; long row0; const float* bp;
  if (id < 768) {                         // EngineA routed, XCD owns (e,ni)
    const int k = id & 7, t = id >> 3;
    mi = t & 7; const int pid = k * 12 + (t >> 3);
    const int e = pid >> 3; ni = pid & 7;
    live = cnt[e] - mi * 256;
    if (live <= 0) return;
    if (live > 256) live = 256;
    row0 = baseA[e] + mi * 256; e18 = e; bp = ba1 + (long)e * 2048;
  } else {
    id -= 768;
    const int k = id & 7, t = id >> 3;
    mi = t & 7; const int pid = k * 6 + (t >> 3);
    const int e = pid >> 3; ni = pid & 7;
    row0 = 8192L + e * 2048 + mi * 256; live = 256;
    e18 = 12 + e; bp = bg1 + (long)e * 2048;
  }
  const int tid = threadIdx.x;
  const bool routed = (e18 < 12);
  if (tid < 256) {
    const int gi = mi * 256 + tid;
    if (routed) {
      const bool ok = tid < live;
      Lrow[tid] = ok ? rows[e18 * 2048 + gi] : 0;
      Lg[tid]   = ok ? gval[e18 * 2048 + gi] : 0.f;
    } else {
      Lrow[tid] = gi;
      Lg[tid] = wG[gi * 6 + (e18 - 12)];
    }
  }
  __syncthreads();                        // also drains vmcnt before staging
  const int srow = tid >> 2;
  const int sch = ((tid & 3) ^ ((tid >> 3) & 3)) * 8;  // pre-swizzled source chunk
  const f16* pa0 = x + (long)Lrow[srow] * 1024 + sch;
  const f16* pa1 = x + (long)Lrow[128 + srow] * 1024 + sch;
  const f16* pb0 = w1t + (long)e18 * 2048 * 1024 + ((long)ni * 256 + srow) * 1024 + sch;
  const f16* pb1 = pb0 + 128 * 1024;
  const int wave = tid >> 6, lane = tid & 63;
  const int wm = wave & 1, wn = wave >> 1;
  const int l16 = lane & 15, q = lane >> 4;
  const int qa = (q ^ ((l16 >> 1) & 3)) * 8;
  const int arow = wm * 128 + l16;
  const int brow = wn * 64 + l16;
  f32x4 acc[8][4] = {};
  f16x8 av[8], bv[2];
  // prologue: tile0 (all 4 regions) + tile1 kh0; oldest 4 loads drained
  ST_A(0, 0, 0) ST_B(0, 0, 0) ST_A(0, 0, 1) ST_B(0, 0, 1) ST_A(1, 1, 0) ST_B(1, 1, 0)
  WVM8(); BARX(); SB0();
#pragma unroll 1
  for (int kt = 0; kt < NKC; kt += 2) { GTILE(kt, 0) GTILE(kt + 1, 1) }
  WVM0();
  // epilogue: relu + gate + bias, store h (row stride 2048)
#pragma unroll
  for (int i = 0; i < 8; i++) {
#pragma unroll
    for (int r = 0; r < 4; r++) {
      const int lr = wm * 128 + i * 16 + q * 4 + r;
      if (lr < live) {
        const float wv = Lg[lr];
        f16* C = h + (row0 + lr) * 2048 + ni * 256;
#pragma unroll
        for (int jj = 0; jj < 4; jj++) {
          const int cc = wn * 64 + jj * 16 + l16;
          const float v = fmaxf(acc[i][jj][r] + bp[ni * 256 + cc], 0.f) * wv;
          C[cc] = (f16)v;
        }
      }
    }
  }
}

// ------------------------------------------------ unified GEMM2 (18 experts)
// res[row] = h[row] @ w2t[e18]^T ; 8-phase, BM=BN=256, BK=64, K=2048
// grid 576: ids 0..383 EngineA routed, 384..575 EngineG dense. Static map.
__global__ __launch_bounds__(512, 2) void gemm2_kernel(
    const f16* __restrict__ h, const f16* __restrict__ w2t,
    f16* __restrict__ res, const int* __restrict__ cnt,
    const int* __restrict__ baseA) {
  constexpr int NKC = 32;                 // K=2048 / 64
  __shared__ f16 Al[2][2][8192];
  __shared__ f16 Bl[2][2][8192];
  int id = blockIdx.x;
  int e18, mi, ni, live; long row0;
  if (id < 384) {                         // 12 exp * 8 mi * 4 ni
    const int k = id & 7, t = id >> 3;
    mi = t & 7; const int pid = k * 6 + (t >> 3);
    const int e = pid >> 2; ni = pid & 3;
    live = cnt[e] - mi * 256;
    if (live <= 0) return;
    if (live > 256) live = 256;
    row0 = baseA[e] + mi * 256; e18 = e;
  } else {
    id -= 384;                            // 6 exp * 8 mi * 4 ni
    const int k = id & 7, t = id >> 3;
    mi = t & 7; const int pid = k * 3 + (t >> 3);
    const int e = pid >> 2; ni = pid & 3;
    row0 = 8192L + e * 2048 + mi * 256; live = 256; e18 = 12 + e;
  }
  const int tid = threadIdx.x;
  const int srow = tid >> 2;
  const int sch = ((tid & 3) ^ ((tid >> 3) & 3)) * 8;
  const f16* pa0 = h + (row0 + srow) * 2048 + sch;
  const f16* pa1 = pa0 + 128 * 2048;
  const f16* pb0 = w2t + (long)e18 * 1024 * 2048 + ((long)ni * 256 + srow) * 2048 + sch;
  const f16* pb1 = pb0 + 128 * 2048;
  const int wave = tid >> 6, lane = tid & 63;
  const int wm = wave & 1, wn = wave >> 1;
  const int l16 = lane & 15, q = lane >> 4;
  const int qa = (q ^ ((l16 >> 1) & 3)) * 8;
  const int arow = wm * 128 + l16;
  const int brow = wn * 64 + l16;
  f32x4 acc[8][4] = {};
  f16x8 av[8], bv[2];
  ST_A(0, 0, 0) ST_B(0, 0, 0) ST_A(0, 0, 1) ST_B(0, 0, 1) ST_A(1, 1, 0) ST_B(1, 1, 0)
  WVM8(); BARX(); SB0();
#pragma unroll 1
  for (int kt = 0; kt < NKC; kt += 2) { GTILE(kt, 0) GTILE(kt + 1, 1) }
  WVM0();
#pragma unroll
  for (int i = 0; i < 8; i++) {
#pragma unroll
    for (int r = 0; r < 4; r++) {
      const int lr = wm * 128 + i * 16 + q * 4 + r;
      if (lr < live) {
        f16* C = res + (row0 + lr) * 1024 + ni * 256 + wn * 64 + l16;
#pragma unroll
        for (int jj = 0; jj < 4; jj++) C[jj * 16] = (f16)acc[i][jj][r];
      }
    }
  }
}

// ------------------------------------------------ small dense GEMM (dbuf)
// BK=64; LDS rows 128 B; chunk swizzle phys = (hf*4+q) ^ (row&7), staged via
// pre-swizzled global source (linear LDS dest), read with same involution.

struct GA {
  const f16* A; long lda;
  const f16* B; long ldb;
  int nk;                      // K / 64
  float* Cf; f16* Ch;
  const float* bias;
  const float* op; const float* om;
  const float* pt; const float* ts;
  float* pt_out; float* tsum_out;
  const float* ent; const float* tsb; float* aux_out;  // EPI==4 aux fusion
};

// BM=BN=64. EPI: 2 tanh->f16 ; 3 mod+tension ; 4 final output (+aux in block 0,0)
template <int EPI>
__global__ __launch_bounds__(256) void gemm_s(GA a) {
  __shared__ f16 Al[2][64 * 64];
  __shared__ f16 Bl[2][64 * 64];
  const int tid = threadIdx.x;
  const int wave = tid >> 6, lane = tid & 63;
  const int wm = wave & 1, wn = wave >> 1;
  const int l16 = lane & 15, q = lane >> 4;
  const long m0 = (long)blockIdx.y * 64;
  const long n0 = (long)blockIdx.x * 64;
  const int srow = tid >> 3;
  const int sch  = ((tid & 7) ^ (srow & 7)) * 8;
  const f16* a0 = a.A + (m0 + srow) * a.lda + sch;
  const f16* a1 = a.A + (m0 + srow + 32) * a.lda + sch;
  const f16* b0 = a.B + (n0 + srow) * a.ldb + sch;
  const f16* b1 = a.B + (n0 + srow + 32) * a.ldb + sch;
  const int rx = (l16 & 7) * 8;
  f32x4 acc[2][2] = {};
  LOAD_LDS16(a0, &Al[0][tid * 8]);
  LOAD_LDS16(a1, &Al[0][(256 + tid) * 8]);
  LOAD_LDS16(b0, &Bl[0][tid * 8]);
  LOAD_LDS16(b1, &Bl[0][(256 + tid) * 8]);
  for (int kk = 0; kk < a.nk; ++kk) {
    __syncthreads();
    const int cur = kk & 1;
    if (kk + 1 < a.nk) {
      const long k0 = (long)(kk + 1) * 64;
      const int nb = cur ^ 1;
      LOAD_LDS16(a0 + k0, &Al[nb][tid * 8]);
      LOAD_LDS16(a1 + k0, &Al[nb][(256 + tid) * 8]);
      LOAD_LDS16(b0 + k0, &Bl[nb][tid * 8]);
      LOAD_LDS16(b1 + k0, &Bl[nb][(256 + tid) * 8]);
    }
    f16x8 avv[2][2], bvv[2][2];
#pragma unroll
    for (int hf = 0; hf < 2; hf++) {
      const int cA = (((hf * 4 + q) * 8) ^ rx);
#pragma unroll
      for (int i = 0; i < 2; i++)
        avv[hf][i] = *(const f16x8*)&Al[cur][(wm * 32 + i * 16 + l16) * 64 + cA];
#pragma unroll
      for (int j = 0; j < 2; j++)
        bvv[hf][j] = *(const f16x8*)&Bl[cur][(wn * 32 + j * 16 + l16) * 64 + cA];
    }
#pragma unroll
    for (int hf = 0; hf < 2; hf++)
#pragma unroll
      for (int i = 0; i < 2; i++)
#pragma unroll
        for (int j = 0; j < 2; j++)
          acc[i][j] = __builtin_amdgcn_mfma_f32_16x16x32_f16(avv[hf][i], bvv[hf][j], acc[i][j], 0, 0, 0);
  }
  if constexpr (EPI == 2) {
#pragma unroll
    for (int i = 0; i < 2; i++)
#pragma unroll
      for (int r = 0; r < 4; r++) {
        const long gr = m0 + wm * 32 + i * 16 + q * 4 + r;
#pragma unroll
        for (int j = 0; j < 2; j++) {
          const int gc = (int)n0 + wn * 32 + j * 16 + l16;
          a.Ch[gr * 1024 + gc] = (f16)tanhf(acc[i][j][r] + a.bias[gc]);
        }
      }
  } else if constexpr (EPI == 3) {
    float wave_ss = 0.f;
#pragma unroll
    for (int i = 0; i < 2; i++)
#pragma unroll
      for (int r = 0; r < 4; r++) {
        const long gr = m0 + wm * 32 + i * 16 + q * 4 + r;
        float ss = 0.f;
#pragma unroll
        for (int j = 0; j < 2; j++) {
          const int gc = (int)n0 + wn * 32 + j * 16 + l16;
          const long ix = gr * 1024 + gc;
          const float v = (a.op[ix] - a.om[ix]) + acc[i][j][r] + a.bias[gc];
          a.Ch[ix] = (f16)v;
          ss += v * v;
        }
        ss += __shfl_xor(ss, 1); ss += __shfl_xor(ss, 2);
        ss += __shfl_xor(ss, 4); ss += __shfl_xor(ss, 8);
        if (l16 == 0) {
          atomicAdd(a.pt_out + gr, ss);
          wave_ss += ss;
        }
      }
    wave_ss += __shfl_xor(wave_ss, 16);
    wave_ss += __shfl_xor(wave_ss, 32);
    if (lane == 0) atomicAdd(a.tsum_out, wave_ss);
  } else {  // EPI == 4
    const float tsc = a.ts[0];
#pragma unroll
    for (int i = 0; i < 2; i++)
#pragma unroll
      for (int r = 0; r < 4; r++) {
        const long gr = m0 + wm * 32 + i * 16 + q * 4 + r;
        const float sq = sqrtf(a.pt[gr] + 1e-8f) * tsc;
#pragma unroll
        for (int j = 0; j < 2; j++) {
          const int gc = (int)n0 + wn * 32 + j * 16 + l16;
          const long ix = gr * 1024 + gc;
          const float v = tanhf(acc[i][j][r] + a.bias[gc]);
          a.Cf[ix] = 0.5f * (a.op[ix] + a.om[ix]) + sq * v;
        }
      }
    // aux loss fused into block (0,0): all tsb[0..3] were written before launch
    if (blockIdx.x == 0 && blockIdx.y == 0) {
      float s = 0.f;
      for (int i = tid; i < 2048; i += 256) s += a.ent[i];
#pragma unroll
      for (int m = 1; m < 64; m <<= 1) s += __shfl_xor(s, m);
      __shared__ float rwa[4];
      if ((tid & 63) == 0) rwa[tid >> 6] = s;
      __syncthreads();
      if (tid == 0) {
        const float hh = (rwa[0] + rwa[1] + rwa[2] + rwa[3]) * (1.f / 2048.f);
        const float dd = hh - 1.0114042647f;
        const float el = dd * dd;
        const float t0 = a.tsb[0] * (1.f / 2048.f), t1 = a.tsb[1] * (1.f / 2048.f);
        const float t2 = a.tsb[2] * (1.f / 2048.f), t3 = a.tsb[3] * (1.f / 2048.f);
        const float conv = (fabsf(t1 - t0) + fabsf(t2 - t1) + fabsf(t3 - t2)) * (1.f / 3.f);
        a.aux_out[0] = el + 0.001f * conv;
      }
    }
  }
}

// ---------------------------------------------------------------- launcher

extern "C" void kernel_launch(void* const* d_in, const int* in_sizes, int n_in,
                              void* d_out, int out_size, void* d_ws, size_t ws_size,
                              hipStream_t stream) {
  (void)in_sizes; (void)n_in; (void)out_size; (void)ws_size;
  const float* x    = (const float*)d_in[0];
  const float* gaw  = (const float*)d_in[1];
  const float* gab  = (const float*)d_in[2];
  const float* wa1  = (const float*)d_in[3];
  const float* ba1  = (const float*)d_in[4];
  const float* wa2  = (const float*)d_in[5];
  const float* ba2  = (const float*)d_in[6];
  const float* ggw  = (const float*)d_in[7];
  const float* ggb  = (const float*)d_in[8];
  const float* wg1  = (const float*)d_in[9];
  const float* bg1  = (const float*)d_in[10];
  const float* wg2  = (const float*)d_in[11];
  const float* bg2  = (const float*)d_in[12];
  const float* smw1 = (const float*)d_in[13];
  const float* smb1 = (const float*)d_in[14];
  const float* smw2 = (const float*)d_in[15];
  const float* smb2 = (const float*)d_in[16];
  const float* siw  = (const float*)d_in[17];
  const float* sib  = (const float*)d_in[18];
  const float* ftw  = (const float*)d_in[19];
  const float* ftb  = (const float*)d_in[20];
  const float* tsc  = (const float*)d_in[21];

  char* p = (char*)d_ws;
  size_t off = 0;
  auto alloc = [&](size_t bytes) -> char* {
    char* r = p + off;
    off = (off + bytes + 255) & ~(size_t)255;
    return r;
  };
  f16* xb     = (f16*)alloc(2048UL * 1024 * 2);
  f16* w1t    = (f16*)alloc(18UL * 2048 * 1024 * 2);   // later reused as w2t
  f16* smw2t  = (f16*)alloc(1024UL * 2048 * 2);
  f16* sit    = (f16*)alloc(1024UL * 1024 * 2);
  f16* ftt    = (f16*)alloc(1024UL * 1024 * 2);
  f16* h      = (f16*)alloc(20480UL * 2048 * 2);       // 8192 A-compact + 6*2048 G
  f16* res    = (f16*)alloc(20480UL * 1024 * 2);
  float* outP = (float*)alloc(2048UL * 1024 * 4);
  float* outM = (float*)alloc(2048UL * 1024 * 4);
  f16* hsmb   = (f16*)alloc(2048UL * 2048 * 2);
  f16* sst    = (f16*)alloc(2048UL * 1024 * 2);
  f16* modb   = (f16*)alloc(2048UL * 1024 * 2);
  float* entb = (float*)alloc(2048 * 4);
  float* wGb  = (float*)alloc(2048 * 6 * 4);
  float* ptb  = (float*)alloc(4 * 2048 * 4);           // 32768 B
  float* tsb  = (float*)alloc(4 * 4);                  // +32768 (rounds to 256)
  int*   cntb = (int*)alloc(12 * 4);                   // +33024
  int*   baseAb = (int*)alloc(12 * 4);
  int*   rowsb  = (int*)alloc(12 * 2048 * 4);
  float* gvalb  = (float*)alloc(12 * 2048 * 4);
  int*   eAb    = (int*)alloc(2048 * 4 * 4);
  int*   posAb  = (int*)alloc(2048 * 4 * 4);
  float* wA4b   = (float*)alloc(2048 * 4 * 4);

  f16* w2t = w1t;  // [18][1024][2048], reused after gemm1

  // zero tension accumulators + expert counters (contiguous region)
  hipMemsetAsync(ptb, 0, 33072, stream);

  // weight conversion + transpose to [N][K] fp16 (wa1+wg1 in ONE launch)
  transpose_cast2<<<dim3(32, 16, 18), 256, 0, stream>>>(wa1, wg1, 12, w1t,
      1024, 2048, 1024L * 2048, 2048L * 1024, 1024);
  // the three small transposes in ONE launch
  {
    TDesc3 td;
    td.m[0] = {smw2, smw2t, 2048, 1024, 2048};
    td.m[1] = {siw,  sit,  1024, 1024, 1024};
    td.m[2] = {ftw,  ftt,  1024, 1024, 1024};
    transpose3<<<dim3(16, 32, 3), 256, 0, stream>>>(td);
  }
  gating_kernel<<<2048, 256, 0, stream>>>(x, gaw, gab, ggw, ggb, xb, wGb, entb,
                                          rowsb, gvalb, cntb, eAb, posAb, wA4b);
  base_kernel<<<1, 64, 0, stream>>>(cntb, baseAb);

  // unified GEMM1 (A routed + G dense), 8-phase 256^2, static XCD-major
  gemm1_kernel<<<1152, 512, 0, stream>>>(xb, w1t, ba1, bg1, h,
                                         rowsb, gvalb, cntb, baseAb, wGb);

  // layer-2 weights into the (now dead) w1t region (wa2+wg2 in ONE launch)
  transpose_cast2<<<dim3(16, 32, 18), 256, 0, stream>>>(wa2, wg2, 12, w2t,
      2048, 1024, 2048L * 1024, 1024L * 2048, 2048);

  // unified GEMM2, 8-phase 256^2, static XCD-major, compact f16 out
  gemm2_kernel<<<576, 512, 0, stream>>>(h, w2t, res, cntb, baseAb);

  combine_kernel<<<2048, 256, 0, stream>>>(res, eAb, posAb, wA4b, wGb, baseAb,
                                           ba2, bg2, outP, outM, ptb, tsb);

  for (int s = 0; s < 3; s++) {
    hsm_kernel<<<dim3(8, 32), 256, 0, stream>>>(ptb + s * 2048, tsb + s, smw1, smb1, hsmb, s);
    GA g3{};
    g3.A = hsmb; g3.lda = 2048; g3.B = smw2t; g3.ldb = 2048; g3.nk = 32;
    g3.Ch = sst; g3.bias = smb2;
    gemm_s<2><<<dim3(16, 32), 256, 0, stream>>>(g3);
    GA g4{};
    g4.A = sst; g4.lda = 1024; g4.B = sit; g4.ldb = 1024; g4.nk = 16;
    g4.Ch = modb; g4.bias = sib; g4.op = outP; g4.om = outM;
    g4.pt_out = ptb + (s + 1) * 2048; g4.tsum_out = tsb + (s + 1);
    gemm_s<3><<<dim3(16, 32), 256, 0, stream>>>(g4);
  }

  GA g5{};
  g5.A = modb; g5.lda = 1024; g5.B = ftt; g5.ldb = 1024; g5.nk = 16;
  g5.Cf = (float*)d_out; g5.bias = ftb; g5.op = outP; g5.om = outM;
  g5.pt = ptb + 3 * 2048; g5.ts = tsc;
  g5.ent = entb; g5.tsb = tsb; g5.aux_out = (float*)d_out + 2048UL * 1024;
  gemm_s<4><<<dim3(16, 32), 256, 0, stream>>>(g5);
}

// Round 6
// 971.381 us; speedup vs baseline: 1.0342x; 1.0207x over previous
//
#include <hip/hip_runtime.h>

typedef _Float16 f16;
typedef f16  f16x8 __attribute__((ext_vector_type(8)));
typedef f16  f16x4 __attribute__((ext_vector_type(4)));
typedef float f32x4 __attribute__((ext_vector_type(4)));

#define LOAD_LDS16(gp, lp) __builtin_amdgcn_global_load_lds( \
    (const __attribute__((address_space(1))) void*)(gp),     \
    (__attribute__((address_space(3))) void*)(lp), 16, 0, 0)

// ---------------- 8-phase GEMM machinery (kernel-local names expected:
// NKC, Al, Bl, tid, pa0, pa1, pb0, pb1, arow, brow, qa, ava, avb, bvv, acc)
#define BARX() __builtin_amdgcn_s_barrier()
#define SB0() __builtin_amdgcn_sched_barrier(0)
#define WLG0() asm volatile("s_waitcnt lgkmcnt(0)" ::: "memory")
#define WVM8() asm volatile("s_waitcnt vmcnt(8)" ::: "memory")
#define WVM0() asm volatile("s_waitcnt vmcnt(0)" ::: "memory")

// stage one 256x32 region (2 loads/thread). TT clamped at tail so the
// vmcnt(8) position-count stays exact; clamped stages land in free regions.
#define ST_A(TT, BB, KH) { \
  const long ko_ = (long)((TT) < NKC ? (TT) : (NKC - 1)) * 64 + (KH) * 32; \
  LOAD_LDS16(pa0 + ko_, &Al[BB][KH][tid * 8]); \
  LOAD_LDS16(pa1 + ko_, &Al[BB][KH][(512 + tid) * 8]); }
#define ST_B(TT, BB, KH) { \
  const long ko_ = (long)((TT) < NKC ? (TT) : (NKC - 1)) * 64 + (KH) * 32; \
  LOAD_LDS16(pb0 + ko_, &Bl[BB][KH][tid * 8]); \
  LOAD_LDS16(pb1 + ko_, &Bl[BB][KH][(512 + tid) * 8]); }

// balanced register loads: 4 A-frags (one row-half) or 4 B-frags per phase
#define RD_A4(DST, BB, KH, HB) _Pragma("unroll") \
  for (int i_ = 0; i_ < 4; i_++) \
    DST[i_] = *(const f16x8*)&Al[BB][KH][(arow + (HB) * 64 + i_ * 16) * 32 + qa];
#define RD_B4(BB, KH) _Pragma("unroll") \
  for (int j_ = 0; j_ < 4; j_++) \
    bvv[j_] = *(const f16x8*)&Bl[BB][KH][(brow + j_ * 16) * 32 + qa];
// 16-MFMA cluster: one row-half x full 64-col slab, one k-half
#define MFC(AV, OFF) \
  __builtin_amdgcn_s_setprio(1); \
  _Pragma("unroll") \
  for (int i_ = 0; i_ < 4; i_++) \
    _Pragma("unroll") \
    for (int j_ = 0; j_ < 4; j_++) \
      acc[(OFF) + i_][j_] = __builtin_amdgcn_mfma_f32_16x16x32_f16(AV[i_], bvv[j_], acc[(OFF) + i_][j_], 0, 0, 0); \
  __builtin_amdgcn_s_setprio(0);

// one K-tile (BK=64) = 4 phases, ds_reads balanced 8/4/8/4.
// Stage order & vmcnt(8) positions identical to the verified schedule:
// stages kh1 of tile KT+1 (phases 0,1), kh0 of tile KT+2 (phases 2,3).
#define GTILE(KT, BUF) { \
  RD_A4(ava, BUF, 0, 0) RD_B4(BUF, 0) \
  ST_A((KT) + 1, (BUF) ^ 1, 1) \
  BARX(); WLG0(); SB0(); \
  MFC(ava, 0) \
  SB0(); BARX(); \
  RD_A4(avb, BUF, 0, 1) \
  ST_B((KT) + 1, (BUF) ^ 1, 1) \
  WVM8(); \
  BARX(); WLG0(); SB0(); \
  MFC(avb, 4) \
  SB0(); BARX(); \
  RD_A4(ava, BUF, 1, 0) RD_B4(BUF, 1) \
  ST_A((KT) + 2, (BUF), 0) \
  BARX(); WLG0(); SB0(); \
  MFC(ava, 0) \
  SB0(); BARX(); \
  RD_A4(avb, BUF, 1, 1) \
  ST_B((KT) + 2, (BUF), 0) \
  WVM8(); \
  BARX(); WLG0(); SB0(); \
  MFC(avb, 4) \
  SB0(); BARX(); \
}

// ---------------------------------------------------------------- helpers

// 64x64 transpose-cast tile: float4 global loads, f16x4 global stores,
// LDS [64][65] with 2-way-max bank aliasing (free) on both phases.
__device__ __forceinline__ void tr64_tile(const float* __restrict__ s,
                                          f16* __restrict__ d, int C, int dld,
                                          int zr, int zc, int tid) {
  __shared__ float tile[64][65];
  const int tx = tid & 15, ty = tid >> 4;
#pragma unroll
  for (int i = 0; i < 4; i++) {
    const int r = ty + i * 16;
    const float4 v = *(const float4*)(s + (long)(zr + r) * C + zc + tx * 4);
    tile[r][tx * 4 + 0] = v.x; tile[r][tx * 4 + 1] = v.y;
    tile[r][tx * 4 + 2] = v.z; tile[r][tx * 4 + 3] = v.w;
  }
  __syncthreads();
#pragma unroll
  for (int i = 0; i < 4; i++) {
    const int oc = ty + i * 16;                  // source col = dest row
    f16x4 h4;
    h4.x = (f16)tile[tx * 4 + 0][oc];
    h4.y = (f16)tile[tx * 4 + 1][oc];
    h4.z = (f16)tile[tx * 4 + 2][oc];
    h4.w = (f16)tile[tx * 4 + 3][oc];
    *(f16x4*)(d + (long)(zc + oc) * dld + zr + tx * 4) = h4;
  }
}

// two-source batched transpose: z < zsplit reads s0, else s1. Block (0,0,0)
// additionally zeroes [zdst, zdst+zn) ints (folded hipMemsetAsync).
__global__ __launch_bounds__(256) void transpose_cast2(const float* __restrict__ s0,
                                                       const float* __restrict__ s1,
                                                       int zsplit, f16* __restrict__ dst,
                                                       int R, int C, long sbatch,
                                                       long dbatch, int dld,
                                                       int* __restrict__ zdst, int zn) {
  if (zdst && blockIdx.x == 0 && blockIdx.y == 0 && blockIdx.z == 0)
    for (int i = threadIdx.x; i < zn; i += 256) zdst[i] = 0;
  const int z = blockIdx.z;
  const float* s = (z < zsplit) ? (s0 + (long)z * sbatch)
                                : (s1 + (long)(z - zsplit) * sbatch);
  tr64_tile(s, dst + (long)z * dbatch, C, dld,
            blockIdx.y * 64, blockIdx.x * 64, threadIdx.x);
}

// three independent small transposes in one launch (descriptor per z)
struct TDesc { const float* s; f16* d; int R; int C; int dld; };
struct TDesc3 { TDesc m[3]; };

__global__ __launch_bounds__(256) void transpose3(TDesc3 p) {
  const TDesc t = p.m[blockIdx.z];
  const int zc = blockIdx.x * 64;
  const int zr = blockIdx.y * 64;
  if (zr >= t.R || zc >= t.C) return;   // block-uniform exit
  tr64_tile(t.s, t.d, t.C, t.dld, zr, zc, threadIdx.x);
}

// gating: logits, top-4-of-12 (lists + per-row slot map), softmax(6)+entropy.
// Emits xb (f16 cast of x). Last block to finish computes baseA (base fold).
__global__ __launch_bounds__(256) void gating_kernel(
    const float* __restrict__ x, const float* __restrict__ gaw,
    const float* __restrict__ gab, const float* __restrict__ ggw,
    const float* __restrict__ ggb, f16* __restrict__ xb,
    float* __restrict__ wG, float* __restrict__ ent,
    int* __restrict__ rows, float* __restrict__ gval, int* __restrict__ cnt,
    int* __restrict__ eA, int* __restrict__ posA, float* __restrict__ wA4,
    int* __restrict__ baseA, int* __restrict__ done) {
  const int b = blockIdx.x, t = threadIdx.x;
  const float* xr = x + (long)b * 1024;
  float pa[12], pg[6];
#pragma unroll
  for (int e = 0; e < 12; e++) pa[e] = 0.f;
#pragma unroll
  for (int e = 0; e < 6; e++) pg[e] = 0.f;
  const int i0 = t * 4;
  const float4 xv = *(const float4*)(xr + i0);
  f16x4 hx; hx.x = (f16)xv.x; hx.y = (f16)xv.y; hx.z = (f16)xv.z; hx.w = (f16)xv.w;
  *(f16x4*)(xb + (long)b * 1024 + i0) = hx;
  const float xs[4] = {xv.x, xv.y, xv.z, xv.w};
#pragma unroll
  for (int u = 0; u < 4; u++) {
    const float xi = xs[u];
    const float* ga = gaw + (long)(i0 + u) * 12;
    const float* gg = ggw + (long)(i0 + u) * 6;
#pragma unroll
    for (int e = 0; e < 12; e++) pa[e] += xi * ga[e];
#pragma unroll
    for (int e = 0; e < 6; e++) pg[e] += xi * gg[e];
  }
#pragma unroll
  for (int e = 0; e < 12; e++)
    for (int m = 1; m < 64; m <<= 1) pa[e] += __shfl_xor(pa[e], m);
#pragma unroll
  for (int e = 0; e < 6; e++)
    for (int m = 1; m < 64; m <<= 1) pg[e] += __shfl_xor(pg[e], m);
  __shared__ float rw[4][18];
  const int lane = t & 63, wv = t >> 6;
  if (lane == 0) {
#pragma unroll
    for (int e = 0; e < 12; e++) rw[wv][e] = pa[e];
#pragma unroll
    for (int e = 0; e < 6; e++) rw[wv][12 + e] = pg[e];
  }
  __syncthreads();
  if (t == 0) {
    float la[12], lg[6];
#pragma unroll
    for (int e = 0; e < 12; e++)
      la[e] = rw[0][e] + rw[1][e] + rw[2][e] + rw[3][e] + gab[e];
#pragma unroll
    for (int e = 0; e < 6; e++)
      lg[e] = rw[0][12 + e] + rw[1][12 + e] + rw[2][12 + e] + rw[3][12 + e] + ggb[e];
    unsigned used = 0; float tv[4]; int tix[4];
    for (int k = 0; k < 4; k++) {
      float best = -3.4e38f; int bi = 0;
      for (int e = 0; e < 12; e++)
        if (!((used >> e) & 1u) && la[e] > best) { best = la[e]; bi = e; }
      tv[k] = best; tix[k] = bi; used |= 1u << bi;
    }
    const float mx = tv[0];
    float s = 0.f, w4[4];
    for (int k = 0; k < 4; k++) { w4[k] = expf(tv[k] - mx); s += w4[k]; }
    for (int k = 0; k < 4; k++) {
      const float w = w4[k] / s;
      const int e = tix[k];
      const int pos = atomicAdd(&cnt[e], 1);
      rows[e * 2048 + pos] = b;
      gval[e * 2048 + pos] = w;
      eA[b * 4 + k] = e;
      posA[b * 4 + k] = pos;
      wA4[b * 4 + k] = w;
    }
    float mg = lg[0];
    for (int e = 1; e < 6; e++) mg = fmaxf(mg, lg[e]);
    float sg = 0.f, wg6[6];
    for (int e = 0; e < 6; e++) { wg6[e] = expf(lg[e] - mg); sg += wg6[e]; }
    float H = 0.f;
    for (int e = 0; e < 6; e++) {
      const float w = wg6[e] / sg;
      wG[b * 6 + e] = w;
      H -= w * logf(w + 1e-8f);
    }
    ent[b] = H;
    // base fold: last block computes exclusive prefix of cnt (device-scope)
    __threadfence();
    if (atomicAdd(done, 1) == 2047) {
      int r = 0;
      for (int e = 0; e < 12; e++) {
        const int c = atomicAdd(&cnt[e], 0);
        baseA[e] = r; r += c;
      }
    }
  }
}

// combine: out_plus/out_minus from compact res (+res2 split-K partial) +
// gate-weighted biases; tension0; fused hsm step 0 (delta=0, st=0).
__global__ __launch_bounds__(256) void combine_kernel(
    const f16* __restrict__ res, const f16* __restrict__ res2,
    const int* __restrict__ eA,
    const int* __restrict__ posA, const float* __restrict__ wA4,
    const float* __restrict__ wG, const int* __restrict__ baseA,
    const float* __restrict__ ba2, const float* __restrict__ bg2,
    float* __restrict__ outP, float* __restrict__ outM,
    float* __restrict__ pt0, float* __restrict__ ts0,
    const float* __restrict__ smw1, const float* __restrict__ smb1,
    f16* __restrict__ hsmb) {
  const long b = blockIdx.x;
  const int t = threadIdx.x;
  const int c = t * 4;
  float4 P = {0.f, 0.f, 0.f, 0.f}, M = {0.f, 0.f, 0.f, 0.f};
#pragma unroll
  for (int k = 0; k < 4; k++) {
    const int e = eA[b * 4 + k];
    const long slot = baseA[e] + posA[b * 4 + k];
    const f16x4 v = *(const f16x4*)(res + slot * 1024 + c);
    const float w = wA4[b * 4 + k];
    const float4 bb = *(const float4*)(ba2 + (long)e * 1024 + c);
    P.x += (float)v.x + w * bb.x; P.y += (float)v.y + w * bb.y;
    P.z += (float)v.z + w * bb.z; P.w += (float)v.w + w * bb.w;
  }
#pragma unroll
  for (int e = 0; e < 6; e++) {
    const f16x4 v = *(const f16x4*)(res + (8192L + e * 2048 + b) * 1024 + c);
    const float w = wG[b * 6 + e];
    const float4 bb = *(const float4*)(bg2 + (long)e * 1024 + c);
    M.x += (float)v.x + w * bb.x; M.y += (float)v.y + w * bb.y;
    M.z += (float)v.z + w * bb.z; M.w += (float)v.w + w * bb.w;
  }
  if (res2) {  // split-K partial (bias added once above)
#pragma unroll
    for (int k = 0; k < 4; k++) {
      const int e = eA[b * 4 + k];
      const long slot = baseA[e] + posA[b * 4 + k];
      const f16x4 v = *(const f16x4*)(res2 + slot * 1024 + c);
      P.x += (float)v.x; P.y += (float)v.y; P.z += (float)v.z; P.w += (float)v.w;
    }
#pragma unroll
    for (int e = 0; e < 6; e++) {
      const f16x4 v = *(const f16x4*)(res2 + (8192L + e * 2048 + b) * 1024 + c);
      M.x += (float)v.x; M.y += (float)v.y; M.z += (float)v.z; M.w += (float)v.w;
    }
  }
  *(float4*)(outP + b * 1024 + c) = P;
  *(float4*)(outM + b * 1024 + c) = M;
  const float dx = P.x - M.x, dy = P.y - M.y, dz = P.z - M.z, dw = P.w - M.w;
  float s = dx * dx + dy * dy + dz * dz + dw * dw;
#pragma unroll
  for (int m = 1; m < 64; m <<= 1) s += __shfl_xor(s, m);
  __shared__ float rw[4];
  __shared__ float tot_sh;
  if ((t & 63) == 0) rw[t >> 6] = s;
  __syncthreads();
  if (t == 0) {
    const float tot = rw[0] + rw[1] + rw[2] + rw[3];
    pt0[b] = tot;
    atomicAdd(ts0, tot);
    tot_sh = tot;
  }
  __syncthreads();
  // fused hsm step 0: o = tanh(t * u0 + b1)  (delta = 0, st = 0)
  const float tb = tot_sh;
  const int j0 = t * 8;
  f16x8 hv;
#pragma unroll
  for (int u = 0; u < 8; u++)
    hv[u] = (f16)tanhf(tb * smw1[j0 + u] + smb1[j0 + u]);
  *(f16x8*)(hsmb + b * 2048 + j0) = hv;
}

__global__ __launch_bounds__(256) void hsm_kernel(
    const float* __restrict__ pt, const float* __restrict__ tsum,
    const float* __restrict__ w1, const float* __restrict__ b1,
    f16* __restrict__ o, int step) {
  const int j = blockIdx.x * 256 + threadIdx.x;
  const int b0 = blockIdx.y * 64;
  const float u0 = w1[j], u1 = w1[2048 + j], u2 = w1[4096 + j], bb = b1[j];
  const float tm = tsum[0] * (1.f / 2048.f);
  const float st = (float)step * (1.f / 3.f);
#pragma unroll 4
  for (int r = 0; r < 64; r++) {
    const int b = b0 + r;
    const float t = pt[b];
    const float delta = (step == 0) ? 0.f : (t - tm);
    o[(long)b * 2048 + j] = (f16)tanhf(t * u0 + delta * u1 + st * u2 + bb);
  }
}

// ------------------------------------------------ unified GEMM1 (18 experts)
// h[row] = gate * relu(x[src_row] @ w1t[e18]^T + b1[e18])
// 8-phase balanced, BM=BN=256, BK=64, 8 waves, 128 KiB LDS, counted vmcnt(8).
// grid 1152: ids 0..767 EngineA routed, 768..1151 EngineG dense. Static
// XCD-major mapping (k = id&7 owns (e,ni); mi fast) — preserves per-XCD
// B-panel L2 affinity.
__global__ __launch_bounds__(512, 2) void gemm1_kernel(
    const f16* __restrict__ x, const f16* __restrict__ w1t,
    const float* __restrict__ ba1, const float* __restrict__ bg1,
    f16* __restrict__ h, const int* __restrict__ rows,
    const float* __restrict__ gval, const int* __restrict__ cnt,
    const int* __restrict__ baseA, const float* __restrict__ wG) {
  constexpr int NKC = 16;                 // K=1024 / 64
  __shared__ f16 Al[2][2][8192];          // [dbuf][khalf][256 rows x 32 cols]
  __shared__ f16 Bl[2][2][8192];
  __shared__ int   Lrow[256];
  __shared__ float Lg[256];
  int id = blockIdx.x;
  int e18, mi, ni, live; long row0; const float* bp;
  if (id < 768) {                         // EngineA routed, XCD owns (e,ni)
    const int k = id & 7, t = id >> 3;
    mi = t & 7; const int pid = k * 12 + (t >> 3);
    const int e = pid >> 3; ni = pid & 7;
    live = cnt[e] - mi * 256;
    if (live <= 0) return;
    if (live > 256) live = 256;
    row0 = baseA[e] + mi * 256; e18 = e; bp = ba1 + (long)e * 2048;
  } else {
    id -= 768;
    const int k = id & 7, t = id >> 3;
    mi = t & 7; const int pid = k * 6 + (t >> 3);
    const int e = pid >> 3; ni = pid & 7;
    row0 = 8192L + e * 2048 + mi * 256; live = 256;
    e18 = 12 + e; bp = bg1 + (long)e * 2048;
  }
  const int tid = threadIdx.x;
  const bool routed = (e18 < 12);
  if (tid < 256) {
    const int gi = mi * 256 + tid;
    if (routed) {
      const bool ok = tid < live;
      Lrow[tid] = ok ? rows[e18 * 2048 + gi] : 0;
      Lg[tid]   = ok ? gval[e18 * 2048 + gi] : 0.f;
    } else {
      Lrow[tid] = gi;
      Lg[tid] = wG[gi * 6 + (e18 - 12)];
    }
  }
  __syncthreads();                        // also drains vmcnt before staging
  const int srow = tid >> 2;
  const int sch = ((tid & 3) ^ ((tid >> 3) & 3)) * 8;  // pre-swizzled source chunk
  const f16* pa0 = x + (long)Lrow[srow] * 1024 + sch;
  const f16* pa1 = x + (long)Lrow[128 + srow] * 1024 + sch;
  const f16* pb0 = w1t + (long)e18 * 2048 * 1024 + ((long)ni * 256 + srow) * 1024 + sch;
  const f16* pb1 = pb0 + 128 * 1024;
  const int wave = tid >> 6, lane = tid & 63;
  const int wm = wave & 1, wn = wave >> 1;
  const int l16 = lane & 15, q = lane >> 4;
  const int qa = (q ^ ((l16 >> 1) & 3)) * 8;
  const int arow = wm * 128 + l16;
  const int brow = wn * 64 + l16;
  f32x4 acc[8][4] = {};
  f16x8 ava[4], avb[4], bvv[4];
  // prologue: tile0 (all 4 regions) + tile1 kh0; oldest 4 loads drained
  ST_A(0, 0, 0) ST_B(0, 0, 0) ST_A(0, 0, 1) ST_B(0, 0, 1) ST_A(1, 1, 0) ST_B(1, 1, 0)
  WVM8(); BARX(); SB0();
#pragma unroll 1
  for (int kt = 0; kt < NKC; kt += 2) { GTILE(kt, 0) GTILE(kt + 1, 1) }
  WVM0();
  // epilogue: relu + gate + bias, store h (row stride 2048)
#pragma unroll
  for (int i = 0; i < 8; i++) {
#pragma unroll
    for (int r = 0; r < 4; r++) {
      const int lr = wm * 128 + i * 16 + q * 4 + r;
      if (lr < live) {
        const float wv = Lg[lr];
        f16* C = h + (row0 + lr) * 2048 + ni * 256;
#pragma unroll
        for (int jj = 0; jj < 4; jj++) {
          const int cc = wn * 64 + jj * 16 + l16;
          const float v = fmaxf(acc[i][jj][r] + bp[ni * 256 + cc], 0.f) * wv;
          C[cc] = (f16)v;
        }
      }
    }
  }
}

// ------------------------------------------------ unified GEMM2 (18 experts)
// res[row] = h[row] @ w2t[e18]^T ; 8-phase balanced, BM=BN=256.
// SPLIT-K when res2 != null: grid 1152, ids 0..575 K-half 0 -> res,
// 576..1151 K-half 1 -> res2 (NKC=16 each). Else grid 576, NKC=32.
// Static XCD-major mapping within each split half.
__global__ __launch_bounds__(512, 2) void gemm2_kernel(
    const f16* __restrict__ h, const f16* __restrict__ w2t,
    f16* __restrict__ res, f16* __restrict__ res2,
    const int* __restrict__ cnt, const int* __restrict__ baseA) {
  const int NKC = res2 ? 16 : 32;
  __shared__ f16 Al[2][2][8192];
  __shared__ f16 Bl[2][2][8192];
  int id = blockIdx.x;
  f16* out = res; long koff = 0;
  if (id >= 576) { id -= 576; out = res2; koff = 1024; }
  int e18, mi, ni, live; long row0;
  if (id < 384) {                         // 12 exp * 8 mi * 4 ni
    const int k = id & 7, t = id >> 3;
    mi = t & 7; const int pid = k * 6 + (t >> 3);
    const int e = pid >> 2; ni = pid & 3;
    live = cnt[e] - mi * 256;
    if (live <= 0) return;
    if (live > 256) live = 256;
    row0 = baseA[e] + mi * 256; e18 = e;
  } else {
    id -= 384;                            // 6 exp * 8 mi * 4 ni
    const int k = id & 7, t = id >> 3;
    mi = t & 7; const int pid = k * 3 + (t >> 3);
    const int e = pid >> 2; ni = pid & 3;
    row0 = 8192L + e * 2048 + mi * 256; live = 256; e18 = 12 + e;
  }
  const int tid = threadIdx.x;
  const int srow = tid >> 2;
  const int sch = ((tid & 3) ^ ((tid >> 3) & 3)) * 8;
  const f16* pa0 = h + (row0 + srow) * 2048 + koff + sch;
  const f16* pa1 = pa0 + 128 * 2048;
  const f16* pb0 = w2t + (long)e18 * 1024 * 2048 + ((long)ni * 256 + srow) * 2048 + koff + sch;
  const f16* pb1 = pb0 + 128 * 2048;
  const int wave = tid >> 6, lane = tid & 63;
  const int wm = wave & 1, wn = wave >> 1;
  const int l16 = lane & 15, q = lane >> 4;
  const int qa = (q ^ ((l16 >> 1) & 3)) * 8;
  const int arow = wm * 128 + l16;
  const int brow = wn * 64 + l16;
  f32x4 acc[8][4] = {};
  f16x8 ava[4], avb[4], bvv[4];
  ST_A(0, 0, 0) ST_B(0, 0, 0) ST_A(0, 0, 1) ST_B(0, 0, 1) ST_A(1, 1, 0) ST_B(1, 1, 0)
  WVM8(); BARX(); SB0();
#pragma unroll 1
  for (int kt = 0; kt < NKC; kt += 2) { GTILE(kt, 0) GTILE(kt + 1, 1) }
  WVM0();
#pragma unroll
  for (int i = 0; i < 8; i++) {
#pragma unroll
    for (int r = 0; r < 4; r++) {
      const int lr = wm * 128 + i * 16 + q * 4 + r;
      if (lr < live) {
        f16* C = out + (row0 + lr) * 1024 + ni * 256 + wn * 64 + l16;
#pragma unroll
        for (int jj = 0; jj < 4; jj++) C[jj * 16] = (f16)acc[i][jj][r];
      }
    }
  }
}

// ------------------------------------------------ small dense GEMM (dbuf)
// BK=64; LDS rows 128 B; chunk swizzle phys = (hf*4+q) ^ (row&7), staged via
// pre-swizzled global source (linear LDS dest), read with same involution.

struct GA {
  const f16* A; long lda;
  const f16* B; long ldb;
  int nk;                      // K / 64
  float* Cf; f16* Ch;
  const float* bias;
  const float* op; const float* om;
  const float* pt; const float* ts;
  float* pt_out; float* tsum_out;
  const float* ent; const float* tsb; float* aux_out;  // EPI==4 aux fusion
};

// BM=BN=64. EPI: 2 tanh->f16 ; 3 mod+tension ; 4 final output (+aux in block 0,0)
template <int EPI>
__global__ __launch_bounds__(256) void gemm_s(GA a) {
  __shared__ f16 Al[2][64 * 64];
  __shared__ f16 Bl[2][64 * 64];
  const int tid = threadIdx.x;
  const int wave = tid >> 6, lane = tid & 63;
  const int wm = wave & 1, wn = wave >> 1;
  const int l16 = lane & 15, q = lane >> 4;
  const long m0 = (long)blockIdx.y * 64;
  const long n0 = (long)blockIdx.x * 64;
  const int srow = tid >> 3;
  const int sch  = ((tid & 7) ^ (srow & 7)) * 8;
  const f16* a0 = a.A + (m0 + srow) * a.lda + sch;
  const f16* a1 = a.A + (m0 + srow + 32) * a.lda + sch;
  const f16* b0 = a.B + (n0 + srow) * a.ldb + sch;
  const f16* b1 = a.B + (n0 + srow + 32) * a.ldb + sch;
  const int rx = (l16 & 7) * 8;
  f32x4 acc[2][2] = {};
  LOAD_LDS16(a0, &Al[0][tid * 8]);
  LOAD_LDS16(a1, &Al[0][(256 + tid) * 8]);
  LOAD_LDS16(b0, &Bl[0][tid * 8]);
  LOAD_LDS16(b1, &Bl[0][(256 + tid) * 8]);
  for (int kk = 0; kk < a.nk; ++kk) {
    __syncthreads();
    const int cur = kk & 1;
    if (kk + 1 < a.nk) {
      const long k0 = (long)(kk + 1) * 64;
      const int nb = cur ^ 1;
      LOAD_LDS16(a0 + k0, &Al[nb][tid * 8]);
      LOAD_LDS16(a1 + k0, &Al[nb][(256 + tid) * 8]);
      LOAD_LDS16(b0 + k0, &Bl[nb][tid * 8]);
      LOAD_LDS16(b1 + k0, &Bl[nb][(256 + tid) * 8]);
    }
    f16x8 avv[2][2], bvv[2][2];
#pragma unroll
    for (int hf = 0; hf < 2; hf++) {
      const int cA = (((hf * 4 + q) * 8) ^ rx);
#pragma unroll
      for (int i = 0; i < 2; i++)
        avv[hf][i] = *(const f16x8*)&Al[cur][(wm * 32 + i * 16 + l16) * 64 + cA];
#pragma unroll
      for (int j = 0; j < 2; j++)
        bvv[hf][j] = *(const f16x8*)&Bl[cur][(wn * 32 + j * 16 + l16) * 64 + cA];
    }
#pragma unroll
    for (int hf = 0; hf < 2; hf++)
#pragma unroll
      for (int i = 0; i < 2; i++)
#pragma unroll
        for (int j = 0; j < 2; j++)
          acc[i][j] = __builtin_amdgcn_mfma_f32_16x16x32_f16(avv[hf][i], bvv[hf][j], acc[i][j], 0, 0, 0);
  }
  if constexpr (EPI == 2) {
#pragma unroll
    for (int i = 0; i < 2; i++)
#pragma unroll
      for (int r = 0; r < 4; r++) {
        const long gr = m0 + wm * 32 + i * 16 + q * 4 + r;
#pragma unroll
        for (int j = 0; j < 2; j++) {
          const int gc = (int)n0 + wn * 32 + j * 16 + l16;
          a.Ch[gr * 1024 + gc] = (f16)tanhf(acc[i][j][r] + a.bias[gc]);
        }
      }
  } else if constexpr (EPI == 3) {
    float wave_ss = 0.f;
#pragma unroll
    for (int i = 0; i < 2; i++)
#pragma unroll
      for (int r = 0; r < 4; r++) {
        const long gr = m0 + wm * 32 + i * 16 + q * 4 + r;
        float ss = 0.f;
#pragma unroll
        for (int j = 0; j < 2; j++) {
          const int gc = (int)n0 + wn * 32 + j * 16 + l16;
          const long ix = gr * 1024 + gc;
          const float v = (a.op[ix] - a.om[ix]) + acc[i][j][r] + a.bias[gc];
          a.Ch[ix] = (f16)v;
          ss += v * v;
        }
        ss += __shfl_xor(ss, 1); ss += __shfl_xor(ss, 2);
        ss += __shfl_xor(ss, 4); ss += __shfl_xor(ss, 8);
        if (l16 == 0) {
          atomicAdd(a.pt_out + gr, ss);
          wave_ss += ss;
        }
      }
    wave_ss += __shfl_xor(wave_ss, 16);
    wave_ss += __shfl_xor(wave_ss, 32);
    if (lane == 0) atomicAdd(a.tsum_out, wave_ss);
  } else {  // EPI == 4
    const float tsc = a.ts[0];
#pragma unroll
    for (int i = 0; i < 2; i++)
#pragma unroll
      for (int r = 0; r < 4; r++) {
        const long gr = m0 + wm * 32 + i * 16 + q * 4 + r;
        const float sq = sqrtf(a.pt[gr] + 1e-8f) * tsc;
#pragma unroll
        for (int j = 0; j < 2; j++) {
          const int gc = (int)n0 + wn * 32 + j * 16 + l16;
          const long ix = gr * 1024 + gc;
          const float v = tanhf(acc[i][j][r] + a.bias[gc]);
          a.Cf[ix] = 0.5f * (a.op[ix] + a.om[ix]) + sq * v;
        }
      }
    // aux loss fused into block (0,0): all tsb[0..3] were written before launch
    if (blockIdx.x == 0 && blockIdx.y == 0) {
      float s = 0.f;
      for (int i = tid; i < 2048; i += 256) s += a.ent[i];
#pragma unroll
      for (int m = 1; m < 64; m <<= 1) s += __shfl_xor(s, m);
      __shared__ float rwa[4];
      if ((tid & 63) == 0) rwa[tid >> 6] = s;
      __syncthreads();
      if (tid == 0) {
        const float hh = (rwa[0] + rwa[1] + rwa[2] + rwa[3]) * (1.f / 2048.f);
        const float dd = hh - 1.0114042647f;
        const float el = dd * dd;
        const float t0 = a.tsb[0] * (1.f / 2048.f), t1 = a.tsb[1] * (1.f / 2048.f);
        const float t2 = a.tsb[2] * (1.f / 2048.f), t3 = a.tsb[3] * (1.f / 2048.f);
        const float conv = (fabsf(t1 - t0) + fabsf(t2 - t1) + fabsf(t3 - t2)) * (1.f / 3.f);
        a.aux_out[0] = el + 0.001f * conv;
      }
    }
  }
}

// ---------------------------------------------------------------- launcher

extern "C" void kernel_launch(void* const* d_in, const int* in_sizes, int n_in,
                              void* d_out, int out_size, void* d_ws, size_t ws_size,
                              hipStream_t stream) {
  (void)in_sizes; (void)n_in; (void)out_size;
  const float* x    = (const float*)d_in[0];
  const float* gaw  = (const float*)d_in[1];
  const float* gab  = (const float*)d_in[2];
  const float* wa1  = (const float*)d_in[3];
  const float* ba1  = (const float*)d_in[4];
  const float* wa2  = (const float*)d_in[5];
  const float* ba2  = (const float*)d_in[6];
  const float* ggw  = (const float*)d_in[7];
  const float* ggb  = (const float*)d_in[8];
  const float* wg1  = (const float*)d_in[9];
  const float* bg1  = (const float*)d_in[10];
  const float* wg2  = (const float*)d_in[11];
  const float* bg2  = (const float*)d_in[12];
  const float* smw1 = (const float*)d_in[13];
  const float* smb1 = (const float*)d_in[14];
  const float* smw2 = (const float*)d_in[15];
  const float* smb2 = (const float*)d_in[16];
  const float* siw  = (const float*)d_in[17];
  const float* sib  = (const float*)d_in[18];
  const float* ftw  = (const float*)d_in[19];
  const float* ftb  = (const float*)d_in[20];
  const float* tsc  = (const float*)d_in[21];

  char* p = (char*)d_ws;
  size_t off = 0;
  auto alloc = [&](size_t bytes) -> char* {
    char* r = p + off;
    off = (off + bytes + 255) & ~(size_t)255;
    return r;
  };
  f16* xb     = (f16*)alloc(2048UL * 1024 * 2);
  f16* w1t    = (f16*)alloc(18UL * 2048 * 1024 * 2);   // later reused as w2t
  f16* smw2t  = (f16*)alloc(1024UL * 2048 * 2);
  f16* sit    = (f16*)alloc(1024UL * 1024 * 2);
  f16* ftt    = (f16*)alloc(1024UL * 1024 * 2);
  f16* h      = (f16*)alloc(20480UL * 2048 * 2);       // 8192 A-compact + 6*2048 G
  f16* res    = (f16*)alloc(20480UL * 1024 * 2);
  float* outP = (float*)alloc(2048UL * 1024 * 4);
  float* outM = (float*)alloc(2048UL * 1024 * 4);
  f16* hsmb   = (f16*)alloc(2048UL * 2048 * 2);
  f16* sst    = (f16*)alloc(2048UL * 1024 * 2);
  f16* modb   = (f16*)alloc(2048UL * 1024 * 2);
  float* entb = (float*)alloc(2048 * 4);
  float* wGb  = (float*)alloc(2048 * 6 * 4);
  float* ptb  = (float*)alloc(4 * 2048 * 4);           // 32768 B (zeroed below)
  float* tsb  = (float*)alloc(4 * 4);                  // 256-B slot (zeroed)
  int*   cntb = (int*)alloc(12 * 4);                   // (zeroed)
  int*   baseAb = (int*)alloc(12 * 4);
  int*   rowsb  = (int*)alloc(12 * 2048 * 4);
  float* gvalb  = (float*)alloc(12 * 2048 * 4);
  int*   eAb    = (int*)alloc(2048 * 4 * 4);
  int*   posAb  = (int*)alloc(2048 * 4 * 4);
  float* wA4b   = (float*)alloc(2048 * 4 * 4);
  // split-K partial buffer, only if workspace permits (runtime-guarded)
  f16* res2 = nullptr;
  if (off + 20480UL * 1024 * 2 + 256 <= ws_size)
    res2 = (f16*)alloc(20480UL * 1024 * 2);

  f16* w2t = w1t;  // [18][1024][2048], reused after gemm1
  int* done = (int*)tsb + 4;  // within the zeroed 256-B tsb slot

  // weight conversion + transpose (wa1+wg1 in ONE launch); block (0,0,0)
  // zeroes ptb+tsb+cntb (33072 B) — folded hipMemsetAsync
  transpose_cast2<<<dim3(32, 16, 18), 256, 0, stream>>>(wa1, wg1, 12, w1t,
      1024, 2048, 1024L * 2048, 2048L * 1024, 1024, (int*)ptb, 8268);
  // the three small transposes in ONE launch
  {
    TDesc3 td;
    td.m[0] = {smw2, smw2t, 2048, 1024, 2048};
    td.m[1] = {siw,  sit,  1024, 1024, 1024};
    td.m[2] = {ftw,  ftt,  1024, 1024, 1024};
    transpose3<<<dim3(16, 32, 3), 256, 0, stream>>>(td);
  }
  // gating (+ fused baseA prefix via last-block atomic)
  gating_kernel<<<2048, 256, 0, stream>>>(x, gaw, gab, ggw, ggb, xb, wGb, entb,
                                          rowsb, gvalb, cntb, eAb, posAb, wA4b,
                                          baseAb, done);

  // unified GEMM1 (A routed + G dense), 8-phase 256^2, static XCD-major
  gemm1_kernel<<<1152, 512, 0, stream>>>(xb, w1t, ba1, bg1, h,
                                         rowsb, gvalb, cntb, baseAb, wGb);

  // layer-2 weights into the (now dead) w1t region (wa2+wg2 in ONE launch)
  transpose_cast2<<<dim3(16, 32, 18), 256, 0, stream>>>(wa2, wg2, 12, w2t,
      2048, 1024, 2048L * 1024, 1024L * 2048, 2048, nullptr, 0);

  // unified GEMM2, 8-phase 256^2, split-K when res2 available
  gemm2_kernel<<<res2 ? 1152 : 576, 512, 0, stream>>>(h, w2t, res, res2,
                                                      cntb, baseAb);

  // combine (+ split-K merge, + fused hsm step 0)
  combine_kernel<<<2048, 256, 0, stream>>>(res, res2, eAb, posAb, wA4b, wGb,
                                           baseAb, ba2, bg2, outP, outM,
                                           ptb, tsb, smw1, smb1, hsmb);

  for (int s = 0; s < 3; s++) {
    if (s > 0)
      hsm_kernel<<<dim3(8, 32), 256, 0, stream>>>(ptb + s * 2048, tsb + s,
                                                  smw1, smb1, hsmb, s);
    GA g3{};
    g3.A = hsmb; g3.lda = 2048; g3.B = smw2t; g3.ldb = 2048; g3.nk = 32;
    g3.Ch = sst; g3.bias = smb2;
    gemm_s<2><<<dim3(16, 32), 256, 0, stream>>>(g3);
    GA g4{};
    g4.A = sst; g4.lda = 1024; g4.B = sit; g4.ldb = 1024; g4.nk = 16;
    g4.Ch = modb; g4.bias = sib; g4.op = outP; g4.om = outM;
    g4.pt_out = ptb + (s + 1) * 2048; g4.tsum_out = tsb + (s + 1);
    gemm_s<3><<<dim3(16, 32), 256, 0, stream>>>(g4);
  }

  GA g5{};
  g5.A = modb; g5.lda = 1024; g5.B = ftt; g5.ldb = 1024; g5.nk = 16;
  g5.Cf = (float*)d_out; g5.bias = ftb; g5.op = outP; g5.om = outM;
  g5.pt = ptb + 3 * 2048; g5.ts = tsc;
  g5.ent = entb; g5.tsb = tsb; g5.aux_out = (float*)d_out + 2048UL * 1024;
  gemm_s<4><<<dim3(16, 32), 256, 0, stream>>>(g5);
}